// Round 9
// baseline (357.775 us; speedup 1.0000x reference)
//
#include <hip/hip_runtime.h>
#include <stdint.h>

#define DIMC 1536
#define LTOK 3072
#define HEADS 12
#define HD 128
#define FS 384            // H*W = 16*24
#define MAXATTN 1920
#define HTOK 1152         // first token with qf>=3 (chunked rows)
#define NHT 1920          // number of heavy tokens

typedef __attribute__((ext_vector_type(4))) float f32x4;
typedef __attribute__((ext_vector_type(8))) short bf16x8;
typedef __attribute__((ext_vector_type(4))) unsigned int u32x4;

__device__ __forceinline__ unsigned short f2bf(float f) {
  union { float f; unsigned int u; } c; c.f = f;
  unsigned int u = c.u + 0x7fffu + ((c.u >> 16) & 1u);   // RNE
  return (unsigned short)(u >> 16);
}
__device__ __forceinline__ float bf2f(unsigned short s) {
  union { unsigned int u; float f; } c; c.u = (unsigned int)s << 16; return c.f;
}
// packed 2xf32 -> 2xbf16 (RNE), one instruction
__device__ __forceinline__ unsigned int cvtpk(float a, float b) {
  unsigned int r;
  asm("v_cvt_pk_bf16_f32 %0, %1, %2" : "=v"(r) : "v"(a), "v"(b));
  return r;
}

// async global->LDS DMA, 16B per lane; LDS dest must be wave-uniform base +
// lane*16 (all our staging offsets are tid*16B -> satisfied).
__device__ __forceinline__ void dma16(const void* g, void* l) {
  __builtin_amdgcn_global_load_lds(
      (const __attribute__((address_space(1))) unsigned int*)g,
      (__attribute__((address_space(3))) unsigned int*)l, 16, 0, 0);
}

// key permutation inside each 64-key tile (4-token groups stay contiguous):
// group G bits (g3 g2 g1 g0) -> G' = g3*8 + g1*4 + g0*2 + g2, chosen so the
// attention PV B-operand fragment IS the softmax output registers.
__device__ __forceinline__ int vperm4(int G) {
  return (((G >> 3) & 1) << 3) | (((G >> 1) & 1) << 2) | ((G & 1) << 1) | ((G >> 2) & 1);
}

// ---------------- fused fp32 -> bf16 conversion for all 5 tensors ----------------
__global__ __launch_bounds__(256)
void cvt_all_k(const float* __restrict__ x, const float* __restrict__ wq,
               const float* __restrict__ wk, const float* __restrict__ wv,
               const float* __restrict__ wo,
               unsigned short* __restrict__ xb, unsigned short* __restrict__ wqb,
               unsigned short* __restrict__ wkb, unsigned short* __restrict__ wvb,
               unsigned short* __restrict__ wob)
{
  const int i = blockIdx.x * 256 + threadIdx.x;      // uint4 index
  const int n0 = LTOK * DIMC / 4;
  const int nw = DIMC * DIMC / 4;
  const float* src; unsigned short* dst; int off;
  if (i < n0) { src = x; dst = xb; off = i; }
  else {
    int j = i - n0; int w = j / nw; off = j - w * nw;
    src = (w == 0) ? wq : (w == 1) ? wk : (w == 2) ? wv : wo;
    dst = (w == 0) ? wqb : (w == 1) ? wkb : (w == 2) ? wvb : wob;
  }
  float4 f = ((const float4*)src)[off];
  uint2 o;
  o.x = (unsigned int)f2bf(f.x) | ((unsigned int)f2bf(f.y) << 16);
  o.y = (unsigned int)f2bf(f.z) | ((unsigned int)f2bf(f.w) << 16);
  ((uint2*)dst)[off] = o;
}

// ---------------- QKV GEMM: 128x128 tile, BK=64, 256 thr, single-buffer -------
// Single-buffer + XCD-chunked swizzle (T1): flat grid 864 = 8*108,
// f'=(f&7)*108+(f>>3) -> each XCD owns 9 contiguous A-panels.
__global__ __launch_bounds__(256)
void gemm_qkv(const unsigned short* __restrict__ A,
              const unsigned short* __restrict__ B0,
              const unsigned short* __restrict__ B1,
              const unsigned short* __restrict__ B2,
              const float* __restrict__ bias0,
              const float* __restrict__ bias1,
              const float* __restrict__ bias2,
              unsigned short* __restrict__ o0, unsigned short* __restrict__ o1,
              unsigned short* __restrict__ vt)
{
  const int f = blockIdx.x;
  const int fp = (f & 7) * 108 + (f >> 3);      // bijective: 864 = 8*108
  const int z = fp / 288;
  const int rr = fp - z * 288;
  const int by = rr / 12;
  const int bx = rr - by * 12;

  const unsigned short* Bw = (z == 0) ? B0 : (z == 1) ? B1 : B2;
  const float* bias = (z == 0) ? bias0 : (z == 1) ? bias1 : bias2;

  __shared__ __align__(16) unsigned short lA[128 * 64];
  __shared__ __align__(16) unsigned short lB[128 * 64];

  const int tid = threadIdx.x;
  const int wave = tid >> 6;
  const int lane = tid & 63;
  const int m0 = by * 128;
  const int n0 = bx * 128;
  const int wm = (wave >> 1) * 64;
  const int wn = (wave & 1) * 64;

  f32x4 acc[4][4] = {};

  const int srow = tid >> 3;                    // 0..31
  const int scol = ((tid & 7) ^ (srow & 7)) * 8;
  const unsigned short* ga = A  + (size_t)(m0 + srow) * DIMC + scol;
  const unsigned short* gb = Bw + (size_t)(n0 + srow) * DIMC + scol;
  unsigned short* la = lA + tid * 8;
  unsigned short* lb = lB + tid * 8;

  const int fr = lane & 15;
  const int g = lane >> 4;
  const int fx = fr & 7;                        // read-side XOR term

  for (int k0 = 0; k0 < DIMC; k0 += 64) {
    dma16(ga + k0,                     la);
    dma16(ga + k0 + (size_t)32 * DIMC, la + 2048);
    dma16(ga + k0 + (size_t)64 * DIMC, la + 4096);
    dma16(ga + k0 + (size_t)96 * DIMC, la + 6144);
    dma16(gb + k0,                     lb);
    dma16(gb + k0 + (size_t)32 * DIMC, lb + 2048);
    dma16(gb + k0 + (size_t)64 * DIMC, lb + 4096);
    dma16(gb + k0 + (size_t)96 * DIMC, lb + 6144);
    __syncthreads();

#pragma unroll
    for (int kk = 0; kk < 2; ++kk) {
      const int cx = ((kk * 4 + g) ^ fx) * 8;   // swizzled chunk offset
      bf16x8 af[4], bf[4];
#pragma unroll
      for (int i = 0; i < 4; ++i)
        af[i] = *(const bf16x8*)&lA[(wm + i * 16 + fr) * 64 + cx];
#pragma unroll
      for (int j = 0; j < 4; ++j)
        bf[j] = *(const bf16x8*)&lB[(wn + j * 16 + fr) * 64 + cx];
#pragma unroll
      for (int i = 0; i < 4; ++i)
#pragma unroll
        for (int j = 0; j < 4; ++j)
          acc[i][j] = __builtin_amdgcn_mfma_f32_16x16x32_bf16(af[i], bf[j], acc[i][j], 0, 0, 0);
    }
    __syncthreads();
  }

  const int col = lane & 15;
  const int rb = (lane >> 4) * 4;
  if (z < 2) {
    unsigned short* outp = z ? o1 : o0;
#pragma unroll
    for (int j = 0; j < 4; ++j) {
      const int gn = n0 + wn + j * 16 + col;
      const float bv = bias[gn];
#pragma unroll
      for (int i = 0; i < 4; ++i)
#pragma unroll
        for (int r = 0; r < 4; ++r) {
          const int gm = m0 + wm + i * 16 + rb + r;
          outp[(size_t)gm * DIMC + gn] = f2bf(acc[i][j][r] + bv);
        }
    }
  } else {
    // vt[d][tok'] = v[tok][d] + bias, tok' = 64-tile base + vperm4(group)*4 + r
#pragma unroll
    for (int j = 0; j < 4; ++j) {
      const int gn = n0 + wn + j * 16 + col;      // d
      const float bv = bias[gn];
#pragma unroll
      for (int i = 0; i < 4; ++i) {
        const int base = wm + i * 16 + rb;        // within-128, multiple of 4
        const int tile = base & ~63;
        const int toka = m0 + tile + vperm4((base & 63) >> 2) * 4;
        uint2 pk;
        pk.x = (unsigned int)f2bf(acc[i][j][0] + bv) |
               ((unsigned int)f2bf(acc[i][j][1] + bv) << 16);
        pk.y = (unsigned int)f2bf(acc[i][j][2] + bv) |
               ((unsigned int)f2bf(acc[i][j][3] + bv) << 16);
        *(uint2*)(vt + (size_t)gn * LTOK + toka) = pk;
      }
    }
  }
}

// ---------------- wo GEMM: 64x128 tile, BK=64, single-buffer + T1 swizzle -----
// (reverted to R7 config: 128^2 @ 288 blocks lost to grid quantization)
__global__ __launch_bounds__(256)
void gemm_wo(const unsigned short* __restrict__ A,
             const unsigned short* __restrict__ Bw,
             const float* __restrict__ bias,
             float* __restrict__ outp)
{
  const int f = blockIdx.x;
  const int fp = (f & 7) * 72 + (f >> 3);       // bijective: 576 = 8*72
  const int by = fp / 12;
  const int bx = fp - by * 12;

  __shared__ __align__(16) unsigned short lA[64 * 64];
  __shared__ __align__(16) unsigned short lB[128 * 64];

  const int tid = threadIdx.x;
  const int wave = tid >> 6;
  const int lane = tid & 63;
  const int m0 = by * 64;
  const int n0 = bx * 128;
  const int wm = (wave >> 1) * 32;
  const int wn = (wave & 1) * 64;

  f32x4 acc[2][4] = {};

  const int srow = tid >> 3;                    // 0..31
  const int scol = ((tid & 7) ^ (srow & 7)) * 8;
  const unsigned short* ga = A  + (size_t)(m0 + srow) * DIMC + scol;
  const unsigned short* gb = Bw + (size_t)(n0 + srow) * DIMC + scol;
  unsigned short* la = lA + tid * 8;
  unsigned short* lb = lB + tid * 8;

  const int fr = lane & 15;
  const int g = lane >> 4;
  const int fx = fr & 7;

  for (int k0 = 0; k0 < DIMC; k0 += 64) {
    dma16(ga + k0,                     la);
    dma16(ga + k0 + (size_t)32 * DIMC, la + 2048);
    dma16(gb + k0,                     lb);
    dma16(gb + k0 + (size_t)32 * DIMC, lb + 2048);
    dma16(gb + k0 + (size_t)64 * DIMC, lb + 4096);
    dma16(gb + k0 + (size_t)96 * DIMC, lb + 6144);
    __syncthreads();

#pragma unroll
    for (int kk = 0; kk < 2; ++kk) {
      const int cx = ((kk * 4 + g) ^ fx) * 8;
      bf16x8 af[2], bf[4];
#pragma unroll
      for (int i = 0; i < 2; ++i)
        af[i] = *(const bf16x8*)&lA[(wm + i * 16 + fr) * 64 + cx];
#pragma unroll
      for (int j = 0; j < 4; ++j)
        bf[j] = *(const bf16x8*)&lB[(wn + j * 16 + fr) * 64 + cx];
#pragma unroll
      for (int i = 0; i < 2; ++i)
#pragma unroll
        for (int j = 0; j < 4; ++j)
          acc[i][j] = __builtin_amdgcn_mfma_f32_16x16x32_bf16(af[i], bf[j], acc[i][j], 0, 0, 0);
    }
    __syncthreads();
  }

  const int col = lane & 15;
  const int rb = (lane >> 4) * 4;
#pragma unroll
  for (int j = 0; j < 4; ++j) {
    const int gn = n0 + wn + j * 16 + col;
    const float bv = bias[gn];
#pragma unroll
    for (int i = 0; i < 2; ++i)
#pragma unroll
      for (int r = 0; r < 4; ++r) {
        const int gm = m0 + wm + i * 16 + rb + r;
        outp[(size_t)gm * DIMC + gn] = acc[i][j][r] + bv;
      }
  }
}

// ---------------- rmsnorm + 3D RoPE on q/k, vectorized (G13) ------------------
__global__ __launch_bounds__(192)
void post_qkv_k(unsigned short* __restrict__ q, unsigned short* __restrict__ k,
                const float* __restrict__ nqw, const float* __restrict__ nkw,
                const float* __restrict__ freqs)
{
  const int bx = blockIdx.x;
  const int tid = threadIdx.x;
  const int which = bx >= LTOK;
  const int tok = bx - which * LTOK;
  unsigned short* row = (which ? k : q) + (size_t)tok * DIMC;
  const float* nw = which ? nkw : nqw;
  const float sc = which ? 1.f : (0.08838834764831845f * 1.4426950408889634f);
  const int base = tid * 8;

  const bf16x8 rv = *(const bf16x8*)(row + base);
  float vv[8];
  float ss = 0.f;
#pragma unroll
  for (int j = 0; j < 8; ++j) {
    vv[j] = bf2f((unsigned short)rv[j]);
    ss += vv[j] * vv[j];
  }
#pragma unroll
  for (int off = 1; off < 64; off <<= 1) ss += __shfl_xor(ss, off);
  __shared__ float wsum[3];
  if ((tid & 63) == 0) wsum[tid >> 6] = ss;
  __syncthreads();
  const float total = wsum[0] + wsum[1] + wsum[2];
  const float rms = rsqrtf(total * (1.f / DIMC) + 1e-6f);

  const int f = tok / FS;
  const int rem = tok - f * FS;
  const int h = rem / 24;
  const int w = rem - h * 24;

  float nwv[8];
  *(float4*)&nwv[0] = *(const float4*)(nw + base);
  *(float4*)&nwv[4] = *(const float4*)(nw + base + 4);

  u32x4 outp;
#pragma unroll
  for (int pp = 0; pp < 4; ++pp) {
    const int P = (base >> 1) + pp;
    const int p = P & 63;
    const int t = (p < 22) ? f : ((p < 43) ? h : w);
    const float2 fc = *(const float2*)(freqs + t * 128 + p * 2);
    const float e = vv[2 * pp]     * rms * nwv[2 * pp];
    const float o = vv[2 * pp + 1] * rms * nwv[2 * pp + 1];
    outp[pp] = (unsigned int)f2bf((e * fc.x - o * fc.y) * sc) |
               ((unsigned int)f2bf((e * fc.y + o * fc.x) * sc) << 16);
  }
  *(u32x4*)(row + base) = outp;
}

// ---------------- MFMA flash attention v10: 256-row pair blocks ---------------
// LDS-traffic amortization: per frame (384 rows = 3x128), a PAIR block covers
// rows [0,256) with 8 waves x 32 q-rows (two 16-row score sets/wave sharing
// every K/V fragment load: 64 MFMA per 32 ds_read), and a SINGLE block (v6
// path, 8 waves x 16 rows) covers rows [256,384). Halves LDS bytes/q-row and
// K/V HBM staging/q-row on 2/3 of the work; kend is uniform per block.
// Shared per-lane max across the lane's two rows (valid bound; defer-max THR=8
// keeps p <= 2^8). Chunking preserves merge_k's token rule.
#define KBUF (64 * 128)
#define VBUF (128 * 64)
__global__ __launch_bounds__(512, 4)
void attn_flash(const unsigned short* __restrict__ q,
                const unsigned short* __restrict__ k,
                const unsigned short* __restrict__ vt,
                unsigned short* __restrict__ ab,
                float* __restrict__ Opart,
                float* __restrict__ Opart2,
                float* __restrict__ mlbuf)
{
  const int bid = blockIdx.x;
  int f, head, chunk, nch, pair;
  if (bid < 12)       { f = 2; head = bid;        chunk = 0; nch = 1; pair = 1; }
  else if (bid < 36)  { int b = bid - 12;  f = 4; head = b >> 1; chunk = b & 1; nch = 2; pair = 1; }
  else if (bid < 48)  { f = 1; head = bid - 36;   chunk = 0; nch = 1; pair = 1; }
  else if (bid < 72)  { int b = bid - 48;  f = 3; head = b >> 1; chunk = b & 1; nch = 2; pair = 1; }
  else if (bid < 180) { int b = bid - 72;  head = b / 9; int r = b % 9; f = 5 + r / 3; chunk = r % 3; nch = 3; pair = 1; }
  else if (bid < 192) { f = 2; head = bid - 180;  chunk = 0; nch = 1; pair = 0; }
  else if (bid < 216) { int b = bid - 192; f = 4; head = b >> 1; chunk = b & 1; nch = 2; pair = 0; }
  else if (bid < 228) { f = 1; head = bid - 216;  chunk = 0; nch = 1; pair = 0; }
  else if (bid < 252) { int b = bid - 228; f = 3; head = b >> 1; chunk = b & 1; nch = 2; pair = 0; }
  else if (bid < 360) { int b = bid - 252; head = b / 9; int r = b % 9; f = 5 + r / 3; chunk = r % 3; nch = 3; pair = 0; }
  else if (bid < 372) { f = 0; head = bid - 360;  chunk = 0; nch = 1; pair = 1; }
  else                { f = 0; head = bid - 372;  chunk = 0; nch = 1; pair = 0; }

  const int q0 = f * FS + (pair ? 0 : 256);
  const int kend = (f + 1) * FS;
  const int s2 = kend - MAXATTN;
  const bool two = (s2 > FS);
  const int nt1 = (two ? FS : kend) >> 6;
  const int nt  = nt1 + (two ? (MAXATTN >> 6) : 0);
  const int half = nt / nch;
  const int tstart = chunk * half, tend = tstart + half;

  const int tid = threadIdx.x;
  const int wave = tid >> 6, lane = tid & 63;
  const int col = lane & 15;
  const int g = lane >> 4;
  const int g4 = g * 4;

  __shared__ __align__(16) unsigned short Kl[2 * KBUF];
  __shared__ __align__(16) unsigned short Vtl[2 * VBUF];

  // staging addresses (mode-independent)
  const int krow = tid >> 4;
  const int kc8  = ((tid & 15) ^ (krow & 15)) * 8;
  const unsigned short* kg = k + (size_t)krow * DIMC + head * HD + kc8;
  const int vrow = tid >> 3;
  const int vc8  = ((tid & 7) ^ (vrow & 7)) * 8;
  const unsigned short* vg = vt + ((size_t)head * HD + vrow) * LTOK + vc8;
  unsigned short* kl = Kl + tid * 8;
  unsigned short* vl = Vtl + tid * 8;

  {
    const int kb = (tstart < nt1) ? tstart * 64 : s2 + (tstart - nt1) * 64;
    const unsigned short* kp = kg + (size_t)kb * DIMC;
    dma16(kp,                     kl);
    dma16(kp + (size_t)32 * DIMC, kl + 32 * 128);
    const unsigned short* vp = vg + kb;
    dma16(vp,                     vl);
    dma16(vp + (size_t)64 * LTOK, vl + 64 * 64);
  }

  const int vx0 = (g ^ (col & 7)) * 8;
  const int vx1 = ((4 + g) ^ (col & 7)) * 8;

  if (pair) {
    // ---------------- 256-row pair path: 32 q-rows / wave ----------------
    bf16x8 qfA[4], qfB[4];
    {
      const unsigned short* qr0 = q + (size_t)(q0 + wave * 32 + col) * DIMC + head * HD;
#pragma unroll
      for (int kk = 0; kk < 4; ++kk) {
        qfA[kk] = *(const bf16x8*)(qr0 + kk * 32 + g * 8);
        qfB[kk] = *(const bf16x8*)(qr0 + (size_t)16 * DIMC + kk * 32 + g * 8);
      }
    }

    f32x4 o0[8] = {}, o1[8] = {};
    float m0 = -3.0e38f, l0 = 0.f, l1 = 0.f;

    for (int t = tstart; t < tend; ++t) {
      const int kcur = ((t - tstart) & 1) * KBUF;
      const int vcur = ((t - tstart) & 1) * VBUF;
      __syncthreads();

      if (t + 1 < tend) {
        const int kb = (t + 1 < nt1) ? (t + 1) * 64 : s2 + (t + 1 - nt1) * 64;
        const int knxt = KBUF - kcur, vnxt = VBUF - vcur;
        const unsigned short* kp = kg + (size_t)kb * DIMC;
        dma16(kp,                     kl + knxt);
        dma16(kp + (size_t)32 * DIMC, kl + knxt + 32 * 128);
        const unsigned short* vp = vg + kb;
        dma16(vp,                     vl + vnxt);
        dma16(vp + (size_t)64 * LTOK, vl + vnxt + 64 * 64);
      }

      f32x4 sA[4] = {}, sB[4] = {};
      __builtin_amdgcn_s_setprio(1);
#pragma unroll
      for (int kt = 0; kt < 4; ++kt) {
        const unsigned short* kr = &Kl[kcur + (kt * 16 + col) * 128];
#pragma unroll
        for (int kk = 0; kk < 4; ++kk) {
          bf16x8 kfr = *(const bf16x8*)(kr + ((kk * 4 + g) ^ col) * 8);
          sA[kt] = __builtin_amdgcn_mfma_f32_16x16x32_bf16(kfr, qfA[kk], sA[kt], 0, 0, 0);
          sB[kt] = __builtin_amdgcn_mfma_f32_16x16x32_bf16(kfr, qfB[kk], sB[kt], 0, 0, 0);
        }
      }
      __builtin_amdgcn_s_setprio(0);

      // shared per-lane max over the lane's two rows (32 values) + halves
      float a0 = fmaxf(fmaxf(sA[0][0], sA[0][1]), fmaxf(sA[0][2], sA[0][3]));
      float a1 = fmaxf(fmaxf(sA[1][0], sA[1][1]), fmaxf(sA[1][2], sA[1][3]));
      float a2 = fmaxf(fmaxf(sA[2][0], sA[2][1]), fmaxf(sA[2][2], sA[2][3]));
      float a3 = fmaxf(fmaxf(sA[3][0], sA[3][1]), fmaxf(sA[3][2], sA[3][3]));
      float b0 = fmaxf(fmaxf(sB[0][0], sB[0][1]), fmaxf(sB[0][2], sB[0][3]));
      float b1 = fmaxf(fmaxf(sB[1][0], sB[1][1]), fmaxf(sB[1][2], sB[1][3]));
      float b2 = fmaxf(fmaxf(sB[2][0], sB[2][1]), fmaxf(sB[2][2], sB[2][3]));
      float b3 = fmaxf(fmaxf(sB[3][0], sB[3][1]), fmaxf(sB[3][2], sB[3][3]));
      float mx = fmaxf(fmaxf(fmaxf(a0, a1), fmaxf(a2, a3)),
                       fmaxf(fmaxf(b0, b1), fmaxf(b2, b3)));
      mx = fmaxf(mx, __shfl_xor(mx, 16));
      mx = fmaxf(mx, __shfl_xor(mx, 32));

      if (!__all(mx <= m0 + 8.f)) {
        const float mn = fmaxf(m0, mx);
        const float al = exp2f(m0 - mn);
        m0 = mn;
        l0 *= al; l1 *= al;
#pragma unroll
        for (int dt = 0; dt < 8; ++dt) { o0[dt] *= al; o1[dt] *= al; }
      }

      float pa[16], pb[16];
#pragma unroll
      for (int kt = 0; kt < 4; ++kt)
#pragma unroll
        for (int r = 0; r < 4; ++r) {
          pa[kt * 4 + r] = exp2f(sA[kt][r] - m0);
          pb[kt * 4 + r] = exp2f(sB[kt][r] - m0);
        }

      float rsA = (((pa[0] + pa[1]) + (pa[2] + pa[3])) + ((pa[4] + pa[5]) + (pa[6] + pa[7])))
                + (((pa[8] + pa[9]) + (pa[10] + pa[11])) + ((pa[12] + pa[13]) + (pa[14] + pa[15])));
      float rsB = (((pb[0] + pb[1]) + (pb[2] + pb[3])) + ((pb[4] + pb[5]) + (pb[6] + pb[7])))
                + (((pb[8] + pb[9]) + (pb[10] + pb[11])) + ((pb[12] + pb[13]) + (pb[14] + pb[15])));
      rsA += __shfl_xor(rsA, 16);
      rsA += __shfl_xor(rsA, 32);
      rsB += __shfl_xor(rsB, 16);
      rsB += __shfl_xor(rsB, 32);
      l0 += rsA; l1 += rsB;

      u32x4 tA0, tA1, tB0, tB1;
      tA0[0] = cvtpk(pa[0], pa[1]);   tA0[1] = cvtpk(pa[2], pa[3]);
      tA0[2] = cvtpk(pa[4], pa[5]);   tA0[3] = cvtpk(pa[6], pa[7]);
      tA1[0] = cvtpk(pa[8], pa[9]);   tA1[1] = cvtpk(pa[10], pa[11]);
      tA1[2] = cvtpk(pa[12], pa[13]); tA1[3] = cvtpk(pa[14], pa[15]);
      tB0[0] = cvtpk(pb[0], pb[1]);   tB0[1] = cvtpk(pb[2], pb[3]);
      tB0[2] = cvtpk(pb[4], pb[5]);   tB0[3] = cvtpk(pb[6], pb[7]);
      tB1[0] = cvtpk(pb[8], pb[9]);   tB1[1] = cvtpk(pb[10], pb[11]);
      tB1[2] = cvtpk(pb[12], pb[13]); tB1[3] = cvtpk(pb[14], pb[15]);
      const bf16x8 pfA0 = __builtin_bit_cast(bf16x8, tA0);
      const bf16x8 pfA1 = __builtin_bit_cast(bf16x8, tA1);
      const bf16x8 pfB0 = __builtin_bit_cast(bf16x8, tB0);
      const bf16x8 pfB1 = __builtin_bit_cast(bf16x8, tB1);

      __builtin_amdgcn_s_setprio(1);
#pragma unroll
      for (int dt = 0; dt < 8; ++dt) {
        const unsigned short* vr = &Vtl[vcur + (dt * 16 + col) * 64];
        bf16x8 vf0 = *(const bf16x8*)(vr + vx0);
        o0[dt] = __builtin_amdgcn_mfma_f32_16x16x32_bf16(vf0, pfA0, o0[dt], 0, 0, 0);
        o1[dt] = __builtin_amdgcn_mfma_f32_16x16x32_bf16(vf0, pfB0, o1[dt], 0, 0, 0);
        bf16x8 vf1 = *(const bf16x8*)(vr + vx1);
        o0[dt] = __builtin_amdgcn_mfma_f32_16x16x32_bf16(vf1, pfA1, o0[dt], 0, 0, 0);
        o1[dt] = __builtin_amdgcn_mfma_f32_16x16x32_bf16(vf1, pfB1, o1[dt], 0, 0, 0);
      }
      __builtin_amdgcn_s_setprio(0);
    }

    const int qrowA = q0 + wave * 32 + col;
    if (nch == 1) {
      const float i0 = 1.f / l0, i1 = 1.f / l1;
      unsigned short* orA = ab + (size_t)qrowA * DIMC + head * HD;
      unsigned short* orB = orA + (size_t)16 * DIMC;
#pragma unroll
      for (int dt = 0; dt < 8; ++dt) {
        uint2 pk;
        pk.x = (unsigned int)f2bf(o0[dt][0] * i0) | ((unsigned int)f2bf(o0[dt][1] * i0) << 16);
        pk.y = (unsigned int)f2bf(o0[dt][2] * i0) | ((unsigned int)f2bf(o0[dt][3] * i0) << 16);
        *(uint2*)(orA + dt * 16 + g4) = pk;
        pk.x = (unsigned int)f2bf(o1[dt][0] * i1) | ((unsigned int)f2bf(o1[dt][1] * i1) << 16);
        pk.y = (unsigned int)f2bf(o1[dt][2] * i1) | ((unsigned int)f2bf(o1[dt][3] * i1) << 16);
        *(uint2*)(orB + dt * 16 + g4) = pk;
      }
    } else {
      const int tokp0 = qrowA - HTOK;
      float* obA;
      if (chunk < 2)
        obA = Opart + ((size_t)(chunk * NHT + tokp0) * HEADS + head) * HD;
      else
        obA = Opart2 + ((size_t)(tokp0 - 768) * HEADS + head) * HD;
      float* obB = obA + (size_t)16 * HEADS * HD;
#pragma unroll
      for (int dt = 0; dt < 8; ++dt) {
        *(f32x4*)(obA + dt * 16 + g4) = o0[dt];
        *(f32x4*)(obB + dt * 16 + g4) = o1[dt];
      }
      if (lane < 16) {
        float* mlpA = mlbuf + 2 * ((size_t)(chunk * NHT + tokp0) * HEADS + head);
        mlpA[0] = m0; mlpA[1] = l0;
        float* mlpB = mlpA + 2 * (size_t)16 * HEADS;
        mlpB[0] = m0; mlpB[1] = l1;
      }
    }
  } else {
    // ---------------- 128-row single path (v6, unchanged) ----------------
    bf16x8 qfA[4];
    {
      const unsigned short* qr0 = q + (size_t)(q0 + wave * 16 + col) * DIMC + head * HD;
#pragma unroll
      for (int kk = 0; kk < 4; ++kk)
        qfA[kk] = *(const bf16x8*)(qr0 + kk * 32 + g * 8);
    }

    f32x4 o0[8] = {};
    float m0 = -3.0e38f, l0 = 0.f;

    for (int t = tstart; t < tend; ++t) {
      const int kcur = ((t - tstart) & 1) * KBUF;
      const int vcur = ((t - tstart) & 1) * VBUF;
      __syncthreads();

      if (t + 1 < tend) {
        const int kb = (t + 1 < nt1) ? (t + 1) * 64 : s2 + (t + 1 - nt1) * 64;
        const int knxt = KBUF - kcur, vnxt = VBUF - vcur;
        const unsigned short* kp = kg + (size_t)kb * DIMC;
        dma16(kp,                     kl + knxt);
        dma16(kp + (size_t)32 * DIMC, kl + knxt + 32 * 128);
        const unsigned short* vp = vg + kb;
        dma16(vp,                     vl + vnxt);
        dma16(vp + (size_t)64 * LTOK, vl + vnxt + 64 * 64);
      }

      f32x4 sA[4] = {};
      __builtin_amdgcn_s_setprio(1);
#pragma unroll
      for (int kt = 0; kt < 4; ++kt) {
        const unsigned short* kr = &Kl[kcur + (kt * 16 + col) * 128];
#pragma unroll
        for (int kk = 0; kk < 4; ++kk) {
          bf16x8 kfr = *(const bf16x8*)(kr + ((kk * 4 + g) ^ col) * 8);
          sA[kt] = __builtin_amdgcn_mfma_f32_16x16x32_bf16(kfr, qfA[kk], sA[kt], 0, 0, 0);
        }
      }
      __builtin_amdgcn_s_setprio(0);

      float mxa = fmaxf(fmaxf(sA[0][0], sA[0][1]), fmaxf(sA[0][2], sA[0][3]));
      float mxb = fmaxf(fmaxf(sA[1][0], sA[1][1]), fmaxf(sA[1][2], sA[1][3]));
      float mxc = fmaxf(fmaxf(sA[2][0], sA[2][1]), fmaxf(sA[2][2], sA[2][3]));
      float mxd = fmaxf(fmaxf(sA[3][0], sA[3][1]), fmaxf(sA[3][2], sA[3][3]));
      float mx = fmaxf(fmaxf(mxa, mxb), fmaxf(mxc, mxd));
      mx = fmaxf(mx, __shfl_xor(mx, 16));
      mx = fmaxf(mx, __shfl_xor(mx, 32));

      if (!__all(mx <= m0 + 8.f)) {
        const float mn = fmaxf(m0, mx);
        const float al = exp2f(m0 - mn);
        m0 = mn;
        l0 *= al;
#pragma unroll
        for (int dt = 0; dt < 8; ++dt) o0[dt] *= al;
      }

      float p[16];
#pragma unroll
      for (int kt = 0; kt < 4; ++kt)
#pragma unroll
        for (int r = 0; r < 4; ++r)
          p[kt * 4 + r] = exp2f(sA[kt][r] - m0);

      float rs = ((p[0] + p[1]) + (p[2] + p[3])) + ((p[4] + p[5]) + (p[6] + p[7]))
               + ((p[8] + p[9]) + (p[10] + p[11])) + ((p[12] + p[13]) + (p[14] + p[15]));
      rs += __shfl_xor(rs, 16);
      rs += __shfl_xor(rs, 32);
      l0 += rs;

      u32x4 tA0, tA1;
      tA0[0] = cvtpk(p[0], p[1]);   tA0[1] = cvtpk(p[2], p[3]);
      tA0[2] = cvtpk(p[4], p[5]);   tA0[3] = cvtpk(p[6], p[7]);
      tA1[0] = cvtpk(p[8], p[9]);   tA1[1] = cvtpk(p[10], p[11]);
      tA1[2] = cvtpk(p[12], p[13]); tA1[3] = cvtpk(p[14], p[15]);
      const bf16x8 pfA0 = __builtin_bit_cast(bf16x8, tA0);
      const bf16x8 pfA1 = __builtin_bit_cast(bf16x8, tA1);

      __builtin_amdgcn_s_setprio(1);
#pragma unroll
      for (int dt = 0; dt < 8; ++dt) {
        const unsigned short* vr = &Vtl[vcur + (dt * 16 + col) * 64];
        bf16x8 vf0 = *(const bf16x8*)(vr + vx0);
        o0[dt] = __builtin_amdgcn_mfma_f32_16x16x32_bf16(vf0, pfA0, o0[dt], 0, 0, 0);
        bf16x8 vf1 = *(const bf16x8*)(vr + vx1);
        o0[dt] = __builtin_amdgcn_mfma_f32_16x16x32_bf16(vf1, pfA1, o0[dt], 0, 0, 0);
      }
      __builtin_amdgcn_s_setprio(0);
    }

    const int qrow0 = q0 + wave * 16 + col;
    if (nch == 1) {
      const float i0 = 1.f / l0;
      unsigned short* or0 = ab + (size_t)qrow0 * DIMC + head * HD;
#pragma unroll
      for (int dt = 0; dt < 8; ++dt) {
        uint2 pk;
        pk.x = (unsigned int)f2bf(o0[dt][0] * i0) | ((unsigned int)f2bf(o0[dt][1] * i0) << 16);
        pk.y = (unsigned int)f2bf(o0[dt][2] * i0) | ((unsigned int)f2bf(o0[dt][3] * i0) << 16);
        *(uint2*)(or0 + dt * 16 + g4) = pk;
      }
    } else {
      const int tokp0 = qrow0 - HTOK;
      float* ob0;
      if (chunk < 2)
        ob0 = Opart + ((size_t)(chunk * NHT + tokp0) * HEADS + head) * HD;
      else
        ob0 = Opart2 + ((size_t)(tokp0 - 768) * HEADS + head) * HD;
#pragma unroll
      for (int dt = 0; dt < 8; ++dt)
        *(f32x4*)(ob0 + dt * 16 + g4) = o0[dt];
      if (lane < 16) {
        float* mlp0 = mlbuf + 2 * ((size_t)(chunk * NHT + tokp0) * HEADS + head);
        mlp0[0] = m0; mlp0[1] = l0;
      }
    }
  }
}

// ---------------- merge the 2-or-3 K-chunks for heavy rows ----------------
__global__ __launch_bounds__(384)
void merge_k(const float* __restrict__ Opart, const float* __restrict__ Opart2,
             const float* __restrict__ mlbuf, unsigned short* __restrict__ ab)
{
  const int tokp = blockIdx.x;
  const int tid = threadIdx.x;
  const int e = tid * 4;
  const int head = e >> 7;
  const size_t r0 = (size_t)tokp * DIMC + e;
  float4 o0 = *(const float4*)(Opart + r0);
  float4 o1 = *(const float4*)(Opart + (size_t)NHT * DIMC + r0);
  const float* ml0 = mlbuf + 2 * ((size_t)tokp * HEADS + head);
  const float* ml1 = mlbuf + 2 * ((size_t)(NHT + tokp) * HEADS + head);
  const float m0 = ml0[0], l0 = ml0[1], m1 = ml1[0], l1 = ml1[1];

  const bool three = (tokp >= 768);             // tok >= 1920 (f>=5) has a 3rd chunk
  float m2 = -3.0e38f, l2 = 0.f;
  float4 o2 = make_float4(0.f, 0.f, 0.f, 0.f);
  if (three) {
    o2 = *(const float4*)(Opart2 + (size_t)(tokp - 768) * DIMC + e);
    const float* ml2 = mlbuf + 2 * ((size_t)(2 * NHT + tokp) * HEADS + head);
    m2 = ml2[0]; l2 = ml2[1];
  }

  const float mm = fmaxf(fmaxf(m0, m1), m2);
  const float a0 = exp2f(m0 - mm), a1 = exp2f(m1 - mm);
  const float a2 = three ? exp2f(m2 - mm) : 0.f;
  const float inv = 1.f / (l0 * a0 + l1 * a1 + l2 * a2);
  uint2 pk;
  pk.x = (unsigned int)f2bf((o0.x * a0 + o1.x * a1 + o2.x * a2) * inv) |
         ((unsigned int)f2bf((o0.y * a0 + o1.y * a1 + o2.y * a2) * inv) << 16);
  pk.y = (unsigned int)f2bf((o0.z * a0 + o1.z * a1 + o2.z * a2) * inv) |
         ((unsigned int)f2bf((o0.w * a0 + o1.w * a1 + o2.w * a2) * inv) << 16);
  *(uint2*)(ab + (size_t)(HTOK + tokp) * DIMC + e) = pk;
}

// ---------------- launch ----------------
extern "C" void kernel_launch(void* const* d_in, const int* in_sizes, int n_in,
                              void* d_out, int out_size, void* d_ws, size_t ws_size,
                              hipStream_t stream)
{
  (void)in_sizes; (void)n_in; (void)out_size; (void)ws_size;
  const float* x     = (const float*)d_in[0];
  const float* freqs = (const float*)d_in[3];
  const float* wq    = (const float*)d_in[4];
  const float* bq    = (const float*)d_in[5];
  const float* wk    = (const float*)d_in[6];
  const float* bk    = (const float*)d_in[7];
  const float* wv    = (const float*)d_in[8];
  const float* bv    = (const float*)d_in[9];
  const float* wo    = (const float*)d_in[10];
  const float* bo    = (const float*)d_in[11];
  const float* nqw   = (const float*)d_in[12];
  const float* nkw   = (const float*)d_in[13];

  char* ws = (char*)d_ws;
  size_t off = 0;
  auto take = [&](size_t bytes) -> void* {
    void* p = ws + off; off += (bytes + 255) & ~(size_t)255; return p;
  };
  unsigned short* wob = (unsigned short*)take((size_t)DIMC * DIMC * 2);
  unsigned short* qb  = (unsigned short*)take((size_t)LTOK * DIMC * 2);
  unsigned short* kb  = (unsigned short*)take((size_t)LTOK * DIMC * 2);
  unsigned short* vb  = (unsigned short*)take((size_t)LTOK * DIMC * 2);  // slot-2 partials
  unsigned short* ab  = (unsigned short*)take((size_t)LTOK * DIMC * 2);
  unsigned short* vtb = (unsigned short*)take((size_t)LTOK * DIMC * 2);
  unsigned short* xb  = (unsigned short*)take((size_t)LTOK * DIMC * 2);
  unsigned short* wqb = (unsigned short*)take((size_t)DIMC * DIMC * 2);
  unsigned short* wkb = (unsigned short*)take((size_t)DIMC * DIMC * 2);
  unsigned short* wvb = (unsigned short*)take((size_t)DIMC * DIMC * 2);
  float* mlb = (float*)take((size_t)3 * NHT * HEADS * 2 * sizeof(float));
  float* Opart  = (float*)xb;   // slots 0,1: overlays xb+wqb+wkb+wvb (dead after QKV GEMM)
  float* Opart2 = (float*)vb;   // slot 2: 1152 rows (tok>=1920), 7.1 MB <= 9.4 MB

  cvt_all_k<<<dim3(13824), dim3(256), 0, stream>>>(x, wq, wk, wv, wo,
                                                   xb, wqb, wkb, wvb, wob);

  gemm_qkv<<<dim3(864), dim3(256), 0, stream>>>(
      xb, wqb, wkb, wvb, bq, bk, bv, qb, kb, vtb);

  post_qkv_k<<<dim3(2 * LTOK), dim3(192), 0, stream>>>(qb, kb, nqw, nkw, freqs);

  attn_flash<<<dim3(384), dim3(512), 0, stream>>>(qb, kb, vtb, ab, Opart, Opart2, mlb);
  merge_k<<<dim3(NHT), dim3(384), 0, stream>>>(Opart, Opart2, mlb, ab);

  gemm_wo<<<dim3(576), dim3(256), 0, stream>>>(
      ab, wob, bo, (float*)d_out);
}

// Round 10
// 282.366 us; speedup vs baseline: 1.2671x; 1.2671x over previous
//
#include <hip/hip_runtime.h>
#include <stdint.h>

#define DIMC 1536
#define LTOK 3072
#define HEADS 12
#define HD 128
#define FS 384            // H*W = 16*24
#define MAXATTN 1920
#define HTOK 1152         // first token with qf>=3 (chunked rows)
#define NHT 1920          // number of heavy tokens

typedef __attribute__((ext_vector_type(4))) float f32x4;
typedef __attribute__((ext_vector_type(8))) short bf16x8;
typedef __attribute__((ext_vector_type(4))) unsigned int u32x4;

__device__ __forceinline__ unsigned short f2bf(float f) {
  union { float f; unsigned int u; } c; c.f = f;
  unsigned int u = c.u + 0x7fffu + ((c.u >> 16) & 1u);   // RNE
  return (unsigned short)(u >> 16);
}
__device__ __forceinline__ float bf2f(unsigned short s) {
  union { unsigned int u; float f; } c; c.u = (unsigned int)s << 16; return c.f;
}
// packed 2xf32 -> 2xbf16 (RNE), one instruction
__device__ __forceinline__ unsigned int cvtpk(float a, float b) {
  unsigned int r;
  asm("v_cvt_pk_bf16_f32 %0, %1, %2" : "=v"(r) : "v"(a), "v"(b));
  return r;
}

// async global->LDS DMA, 16B per lane; LDS dest must be wave-uniform base +
// lane*16 (all our staging offsets are tid*16B -> satisfied).
__device__ __forceinline__ void dma16(const void* g, void* l) {
  __builtin_amdgcn_global_load_lds(
      (const __attribute__((address_space(1))) unsigned int*)g,
      (__attribute__((address_space(3))) unsigned int*)l, 16, 0, 0);
}

// key permutation inside each 64-key tile (4-token groups stay contiguous):
// group G bits (g3 g2 g1 g0) -> G' = g3*8 + g1*4 + g0*2 + g2, chosen so the
// attention PV B-operand fragment IS the softmax output registers.
__device__ __forceinline__ int vperm4(int G) {
  return (((G >> 3) & 1) << 3) | (((G >> 1) & 1) << 2) | ((G & 1) << 1) | ((G >> 2) & 1);
}

// ---------------- fused fp32 -> bf16 conversion for all 5 tensors ----------------
__global__ __launch_bounds__(256)
void cvt_all_k(const float* __restrict__ x, const float* __restrict__ wq,
               const float* __restrict__ wk, const float* __restrict__ wv,
               const float* __restrict__ wo,
               unsigned short* __restrict__ xb, unsigned short* __restrict__ wqb,
               unsigned short* __restrict__ wkb, unsigned short* __restrict__ wvb,
               unsigned short* __restrict__ wob)
{
  const int i = blockIdx.x * 256 + threadIdx.x;      // uint4 index
  const int n0 = LTOK * DIMC / 4;
  const int nw = DIMC * DIMC / 4;
  const float* src; unsigned short* dst; int off;
  if (i < n0) { src = x; dst = xb; off = i; }
  else {
    int j = i - n0; int w = j / nw; off = j - w * nw;
    src = (w == 0) ? wq : (w == 1) ? wk : (w == 2) ? wv : wo;
    dst = (w == 0) ? wqb : (w == 1) ? wkb : (w == 2) ? wvb : wob;
  }
  float4 f = ((const float4*)src)[off];
  uint2 o;
  o.x = (unsigned int)f2bf(f.x) | ((unsigned int)f2bf(f.y) << 16);
  o.y = (unsigned int)f2bf(f.z) | ((unsigned int)f2bf(f.w) << 16);
  ((uint2*)dst)[off] = o;
}

// ---------------- QKV GEMM: 128x128 tile, BK=64, 256 thr, single-buffer -------
// Single-buffer + XCD-chunked swizzle (T1): flat grid 864 = 8*108,
// f'=(f&7)*108+(f>>3) -> each XCD owns 9 contiguous A-panels.
__global__ __launch_bounds__(256)
void gemm_qkv(const unsigned short* __restrict__ A,
              const unsigned short* __restrict__ B0,
              const unsigned short* __restrict__ B1,
              const unsigned short* __restrict__ B2,
              const float* __restrict__ bias0,
              const float* __restrict__ bias1,
              const float* __restrict__ bias2,
              unsigned short* __restrict__ o0, unsigned short* __restrict__ o1,
              unsigned short* __restrict__ vt)
{
  const int f = blockIdx.x;
  const int fp = (f & 7) * 108 + (f >> 3);      // bijective: 864 = 8*108
  const int z = fp / 288;
  const int rr = fp - z * 288;
  const int by = rr / 12;
  const int bx = rr - by * 12;

  const unsigned short* Bw = (z == 0) ? B0 : (z == 1) ? B1 : B2;
  const float* bias = (z == 0) ? bias0 : (z == 1) ? bias1 : bias2;

  __shared__ __align__(16) unsigned short lA[128 * 64];
  __shared__ __align__(16) unsigned short lB[128 * 64];

  const int tid = threadIdx.x;
  const int wave = tid >> 6;
  const int lane = tid & 63;
  const int m0 = by * 128;
  const int n0 = bx * 128;
  const int wm = (wave >> 1) * 64;
  const int wn = (wave & 1) * 64;

  f32x4 acc[4][4] = {};

  const int srow = tid >> 3;                    // 0..31
  const int scol = ((tid & 7) ^ (srow & 7)) * 8;
  const unsigned short* ga = A  + (size_t)(m0 + srow) * DIMC + scol;
  const unsigned short* gb = Bw + (size_t)(n0 + srow) * DIMC + scol;
  unsigned short* la = lA + tid * 8;
  unsigned short* lb = lB + tid * 8;

  const int fr = lane & 15;
  const int g = lane >> 4;
  const int fx = fr & 7;                        // read-side XOR term

  for (int k0 = 0; k0 < DIMC; k0 += 64) {
    dma16(ga + k0,                     la);
    dma16(ga + k0 + (size_t)32 * DIMC, la + 2048);
    dma16(ga + k0 + (size_t)64 * DIMC, la + 4096);
    dma16(ga + k0 + (size_t)96 * DIMC, la + 6144);
    dma16(gb + k0,                     lb);
    dma16(gb + k0 + (size_t)32 * DIMC, lb + 2048);
    dma16(gb + k0 + (size_t)64 * DIMC, lb + 4096);
    dma16(gb + k0 + (size_t)96 * DIMC, lb + 6144);
    __syncthreads();

#pragma unroll
    for (int kk = 0; kk < 2; ++kk) {
      const int cx = ((kk * 4 + g) ^ fx) * 8;   // swizzled chunk offset
      bf16x8 af[4], bf[4];
#pragma unroll
      for (int i = 0; i < 4; ++i)
        af[i] = *(const bf16x8*)&lA[(wm + i * 16 + fr) * 64 + cx];
#pragma unroll
      for (int j = 0; j < 4; ++j)
        bf[j] = *(const bf16x8*)&lB[(wn + j * 16 + fr) * 64 + cx];
#pragma unroll
      for (int i = 0; i < 4; ++i)
#pragma unroll
        for (int j = 0; j < 4; ++j)
          acc[i][j] = __builtin_amdgcn_mfma_f32_16x16x32_bf16(af[i], bf[j], acc[i][j], 0, 0, 0);
    }
    __syncthreads();
  }

  const int col = lane & 15;
  const int rb = (lane >> 4) * 4;
  if (z < 2) {
    unsigned short* outp = z ? o1 : o0;
#pragma unroll
    for (int j = 0; j < 4; ++j) {
      const int gn = n0 + wn + j * 16 + col;
      const float bv = bias[gn];
#pragma unroll
      for (int i = 0; i < 4; ++i)
#pragma unroll
        for (int r = 0; r < 4; ++r) {
          const int gm = m0 + wm + i * 16 + rb + r;
          outp[(size_t)gm * DIMC + gn] = f2bf(acc[i][j][r] + bv);
        }
    }
  } else {
    // vt[d][tok'] = v[tok][d] + bias, tok' = 64-tile base + vperm4(group)*4 + r
#pragma unroll
    for (int j = 0; j < 4; ++j) {
      const int gn = n0 + wn + j * 16 + col;      // d
      const float bv = bias[gn];
#pragma unroll
      for (int i = 0; i < 4; ++i) {
        const int base = wm + i * 16 + rb;        // within-128, multiple of 4
        const int tile = base & ~63;
        const int toka = m0 + tile + vperm4((base & 63) >> 2) * 4;
        uint2 pk;
        pk.x = (unsigned int)f2bf(acc[i][j][0] + bv) |
               ((unsigned int)f2bf(acc[i][j][1] + bv) << 16);
        pk.y = (unsigned int)f2bf(acc[i][j][2] + bv) |
               ((unsigned int)f2bf(acc[i][j][3] + bv) << 16);
        *(uint2*)(vt + (size_t)gn * LTOK + toka) = pk;
      }
    }
  }
}

// ---------------- wo GEMM: 64x128 tile, BK=64, single-buffer + T1 swizzle -----
// Flat grid 576 = 8*72; A-sharers (12 n-blocks per m-row) co-located per XCD.
// (128^2 @ 288 blocks measured worse: grid quantization at 1.125 blocks/CU.)
__global__ __launch_bounds__(256)
void gemm_wo(const unsigned short* __restrict__ A,
             const unsigned short* __restrict__ Bw,
             const float* __restrict__ bias,
             float* __restrict__ outp)
{
  const int f = blockIdx.x;
  const int fp = (f & 7) * 72 + (f >> 3);       // bijective: 576 = 8*72
  const int by = fp / 12;
  const int bx = fp - by * 12;

  __shared__ __align__(16) unsigned short lA[64 * 64];
  __shared__ __align__(16) unsigned short lB[128 * 64];

  const int tid = threadIdx.x;
  const int wave = tid >> 6;
  const int lane = tid & 63;
  const int m0 = by * 64;
  const int n0 = bx * 128;
  const int wm = (wave >> 1) * 32;
  const int wn = (wave & 1) * 64;

  f32x4 acc[2][4] = {};

  const int srow = tid >> 3;                    // 0..31
  const int scol = ((tid & 7) ^ (srow & 7)) * 8;
  const unsigned short* ga = A  + (size_t)(m0 + srow) * DIMC + scol;
  const unsigned short* gb = Bw + (size_t)(n0 + srow) * DIMC + scol;
  unsigned short* la = lA + tid * 8;
  unsigned short* lb = lB + tid * 8;

  const int fr = lane & 15;
  const int g = lane >> 4;
  const int fx = fr & 7;

  for (int k0 = 0; k0 < DIMC; k0 += 64) {
    dma16(ga + k0,                     la);
    dma16(ga + k0 + (size_t)32 * DIMC, la + 2048);
    dma16(gb + k0,                     lb);
    dma16(gb + k0 + (size_t)32 * DIMC, lb + 2048);
    dma16(gb + k0 + (size_t)64 * DIMC, lb + 4096);
    dma16(gb + k0 + (size_t)96 * DIMC, lb + 6144);
    __syncthreads();

#pragma unroll
    for (int kk = 0; kk < 2; ++kk) {
      const int cx = ((kk * 4 + g) ^ fx) * 8;
      bf16x8 af[2], bf[4];
#pragma unroll
      for (int i = 0; i < 2; ++i)
        af[i] = *(const bf16x8*)&lA[(wm + i * 16 + fr) * 64 + cx];
#pragma unroll
      for (int j = 0; j < 4; ++j)
        bf[j] = *(const bf16x8*)&lB[(wn + j * 16 + fr) * 64 + cx];
#pragma unroll
      for (int i = 0; i < 2; ++i)
#pragma unroll
        for (int j = 0; j < 4; ++j)
          acc[i][j] = __builtin_amdgcn_mfma_f32_16x16x32_bf16(af[i], bf[j], acc[i][j], 0, 0, 0);
    }
    __syncthreads();
  }

  const int col = lane & 15;
  const int rb = (lane >> 4) * 4;
#pragma unroll
  for (int j = 0; j < 4; ++j) {
    const int gn = n0 + wn + j * 16 + col;
    const float bv = bias[gn];
#pragma unroll
    for (int i = 0; i < 2; ++i)
#pragma unroll
      for (int r = 0; r < 4; ++r) {
        const int gm = m0 + wm + i * 16 + rb + r;
        outp[(size_t)gm * DIMC + gn] = acc[i][j][r] + bv;
      }
  }
}

// ---------------- rmsnorm + 3D RoPE on q/k, vectorized (G13) ------------------
// 192 threads x 8 bf16 (16B aligned loads/stores), float4 nw, float2 freqs.
__global__ __launch_bounds__(192)
void post_qkv_k(unsigned short* __restrict__ q, unsigned short* __restrict__ k,
                const float* __restrict__ nqw, const float* __restrict__ nkw,
                const float* __restrict__ freqs)
{
  const int bx = blockIdx.x;
  const int tid = threadIdx.x;
  const int which = bx >= LTOK;
  const int tok = bx - which * LTOK;
  unsigned short* row = (which ? k : q) + (size_t)tok * DIMC;
  const float* nw = which ? nkw : nqw;
  const float sc = which ? 1.f : (0.08838834764831845f * 1.4426950408889634f);
  const int base = tid * 8;

  const bf16x8 rv = *(const bf16x8*)(row + base);
  float vv[8];
  float ss = 0.f;
#pragma unroll
  for (int j = 0; j < 8; ++j) {
    vv[j] = bf2f((unsigned short)rv[j]);
    ss += vv[j] * vv[j];
  }
#pragma unroll
  for (int off = 1; off < 64; off <<= 1) ss += __shfl_xor(ss, off);
  __shared__ float wsum[3];
  if ((tid & 63) == 0) wsum[tid >> 6] = ss;
  __syncthreads();
  const float total = wsum[0] + wsum[1] + wsum[2];
  const float rms = rsqrtf(total * (1.f / DIMC) + 1e-6f);

  const int f = tok / FS;
  const int rem = tok - f * FS;
  const int h = rem / 24;
  const int w = rem - h * 24;

  float nwv[8];
  *(float4*)&nwv[0] = *(const float4*)(nw + base);
  *(float4*)&nwv[4] = *(const float4*)(nw + base + 4);

  u32x4 outp;
#pragma unroll
  for (int pp = 0; pp < 4; ++pp) {
    const int P = (base >> 1) + pp;
    const int p = P & 63;
    const int t = (p < 22) ? f : ((p < 43) ? h : w);
    const float2 fc = *(const float2*)(freqs + t * 128 + p * 2);
    const float e = vv[2 * pp]     * rms * nwv[2 * pp];
    const float o = vv[2 * pp + 1] * rms * nwv[2 * pp + 1];
    outp[pp] = (unsigned int)f2bf((e * fc.x - o * fc.y) * sc) |
               ((unsigned int)f2bf((e * fc.y + o * fc.x) * sc) << 16);
  }
  *(u32x4*)(row + base) = outp;
}

// ---------------- MFMA flash attention v6 (best measured: 68.2us) -------------
// cvt_pk packing, defer-max THR=8, fine chunking (max 15 tiles, grid 576
// launched biggest-chunk-first). R9's pair-block variant spilled (VGPR cap 64
// at (512,4) vs ~160 live state -> 131 MB scratch WRITE); reverted for good.
#define KBUF (64 * 128)
#define VBUF (128 * 64)
__global__ __launch_bounds__(512, 4)
void attn_flash(const unsigned short* __restrict__ q,
                const unsigned short* __restrict__ k,
                const unsigned short* __restrict__ vt,
                unsigned short* __restrict__ ab,
                float* __restrict__ Opart,
                float* __restrict__ Opart2,
                float* __restrict__ mlbuf)
{
  const int bid = blockIdx.x;
  int qb, head, chunk, nch;
  if (bid < 36)       { qb = 6 + bid / 12; head = bid % 12; chunk = 0; nch = 1; }         // 18-tile
  else if (bid < 108) { int b = bid - 36;  qb = 12 + b / 24; int r = b % 24; head = r >> 1; chunk = r & 1; nch = 2; }  // 15-tile
  else if (bid < 432) { int b = bid - 108; qb = 15 + b / 36; int r = b % 36; head = r / 3; chunk = r % 3; nch = 3; }   // 12-tile
  else if (bid < 504) { int b = bid - 432; qb = 9 + b / 24;  int r = b % 24; head = r >> 1; chunk = r & 1; nch = 2; }  // 12-tile
  else if (bid < 540) { int b = bid - 504; qb = 3 + b / 12; head = b % 12; chunk = 0; nch = 1; }  // 12-tile
  else                { int b = bid - 540; qb = b / 12;     head = b % 12; chunk = 0; nch = 1; }  // 6-tile

  const int q0 = qb * 128;
  const int qf = qb / 3;
  const int kend = (qf + 1) * FS;
  const int s2 = kend - MAXATTN;
  const bool two = (s2 > FS);
  const int nt1 = (two ? FS : kend) >> 6;
  const int nt  = nt1 + (two ? (MAXATTN >> 6) : 0);
  const int half = nt / nch;
  const int tstart = chunk * half, tend = tstart + half;

  const int tid = threadIdx.x;
  const int wave = tid >> 6, lane = tid & 63;
  const int col = lane & 15;
  const int g = lane >> 4;
  const int g4 = g * 4;

  __shared__ __align__(16) unsigned short Kl[2 * KBUF];
  __shared__ __align__(16) unsigned short Vtl[2 * VBUF];

  bf16x8 qfA[4];
  {
    const unsigned short* qr0 = q + (size_t)(q0 + wave * 16 + col) * DIMC + head * HD;
#pragma unroll
    for (int kk = 0; kk < 4; ++kk)
      qfA[kk] = *(const bf16x8*)(qr0 + kk * 32 + g * 8);
  }

  f32x4 o0[8] = {};
  float m0 = -3.0e38f, l0 = 0.f;

  const int krow = tid >> 4;
  const int kc8  = ((tid & 15) ^ (krow & 15)) * 8;
  const unsigned short* kg = k + (size_t)krow * DIMC + head * HD + kc8;
  const int vrow = tid >> 3;
  const int vc8  = ((tid & 7) ^ (vrow & 7)) * 8;
  const unsigned short* vg = vt + ((size_t)head * HD + vrow) * LTOK + vc8;
  unsigned short* kl = Kl + tid * 8;
  unsigned short* vl = Vtl + tid * 8;

  {
    const int kb = (tstart < nt1) ? tstart * 64 : s2 + (tstart - nt1) * 64;
    const unsigned short* kp = kg + (size_t)kb * DIMC;
    dma16(kp,                     kl);
    dma16(kp + (size_t)32 * DIMC, kl + 32 * 128);
    const unsigned short* vp = vg + kb;
    dma16(vp,                     vl);
    dma16(vp + (size_t)64 * LTOK, vl + 64 * 64);
  }

  for (int t = tstart; t < tend; ++t) {
    const int kcur = ((t - tstart) & 1) * KBUF;
    const int vcur = ((t - tstart) & 1) * VBUF;
    __syncthreads();

    if (t + 1 < tend) {
      const int kb = (t + 1 < nt1) ? (t + 1) * 64 : s2 + (t + 1 - nt1) * 64;
      const int knxt = KBUF - kcur, vnxt = VBUF - vcur;
      const unsigned short* kp = kg + (size_t)kb * DIMC;
      dma16(kp,                     kl + knxt);
      dma16(kp + (size_t)32 * DIMC, kl + knxt + 32 * 128);
      const unsigned short* vp = vg + kb;
      dma16(vp,                     vl + vnxt);
      dma16(vp + (size_t)64 * LTOK, vl + vnxt + 64 * 64);
    }

    f32x4 sA[4] = {};
    __builtin_amdgcn_s_setprio(1);
#pragma unroll
    for (int kt = 0; kt < 4; ++kt) {
      const unsigned short* kr = &Kl[kcur + (kt * 16 + col) * 128];
#pragma unroll
      for (int kk = 0; kk < 4; ++kk) {
        bf16x8 kfr = *(const bf16x8*)(kr + ((kk * 4 + g) ^ col) * 8);
        sA[kt] = __builtin_amdgcn_mfma_f32_16x16x32_bf16(kfr, qfA[kk], sA[kt], 0, 0, 0);
      }
    }
    __builtin_amdgcn_s_setprio(0);

    // row max (tree) over 16 local scores + cross-lane halves
    float mxa = fmaxf(fmaxf(sA[0][0], sA[0][1]), fmaxf(sA[0][2], sA[0][3]));
    float mxb = fmaxf(fmaxf(sA[1][0], sA[1][1]), fmaxf(sA[1][2], sA[1][3]));
    float mxc = fmaxf(fmaxf(sA[2][0], sA[2][1]), fmaxf(sA[2][2], sA[2][3]));
    float mxd = fmaxf(fmaxf(sA[3][0], sA[3][1]), fmaxf(sA[3][2], sA[3][3]));
    float mx = fmaxf(fmaxf(mxa, mxb), fmaxf(mxc, mxd));
    mx = fmaxf(mx, __shfl_xor(mx, 16));
    mx = fmaxf(mx, __shfl_xor(mx, 32));

    // defer-max: only rescale when the tile max exceeds running max by >8
    if (!__all(mx <= m0 + 8.f)) {
      const float mn = fmaxf(m0, mx);
      const float al = exp2f(m0 - mn);
      m0 = mn;
      l0 *= al;
#pragma unroll
      for (int dt = 0; dt < 8; ++dt) o0[dt] *= al;
    }

    float p[16];
#pragma unroll
    for (int kt = 0; kt < 4; ++kt)
#pragma unroll
      for (int r = 0; r < 4; ++r)
        p[kt * 4 + r] = exp2f(sA[kt][r] - m0);

    float rs = ((p[0] + p[1]) + (p[2] + p[3])) + ((p[4] + p[5]) + (p[6] + p[7]))
             + ((p[8] + p[9]) + (p[10] + p[11])) + ((p[12] + p[13]) + (p[14] + p[15]));
    rs += __shfl_xor(rs, 16);
    rs += __shfl_xor(rs, 32);
    l0 += rs;

    u32x4 tA0, tA1;
    tA0[0] = cvtpk(p[0], p[1]);   tA0[1] = cvtpk(p[2], p[3]);
    tA0[2] = cvtpk(p[4], p[5]);   tA0[3] = cvtpk(p[6], p[7]);
    tA1[0] = cvtpk(p[8], p[9]);   tA1[1] = cvtpk(p[10], p[11]);
    tA1[2] = cvtpk(p[12], p[13]); tA1[3] = cvtpk(p[14], p[15]);
    const bf16x8 pfA0 = __builtin_bit_cast(bf16x8, tA0);
    const bf16x8 pfA1 = __builtin_bit_cast(bf16x8, tA1);

    const int vx0 = (g ^ (col & 7)) * 8;
    const int vx1 = ((4 + g) ^ (col & 7)) * 8;
    __builtin_amdgcn_s_setprio(1);
#pragma unroll
    for (int dt = 0; dt < 8; ++dt) {
      const unsigned short* vr = &Vtl[vcur + (dt * 16 + col) * 64];
      bf16x8 vf0 = *(const bf16x8*)(vr + vx0);
      o0[dt] = __builtin_amdgcn_mfma_f32_16x16x32_bf16(vf0, pfA0, o0[dt], 0, 0, 0);
      bf16x8 vf1 = *(const bf16x8*)(vr + vx1);
      o0[dt] = __builtin_amdgcn_mfma_f32_16x16x32_bf16(vf1, pfA1, o0[dt], 0, 0, 0);
    }
    __builtin_amdgcn_s_setprio(0);
  }

  const int qrow0 = q0 + wave * 16 + col;
  if (nch == 1) {
    const float i0 = 1.f / l0;
    unsigned short* or0 = ab + (size_t)qrow0 * DIMC + head * HD;
#pragma unroll
    for (int dt = 0; dt < 8; ++dt) {
      uint2 pk;
      pk.x = (unsigned int)f2bf(o0[dt][0] * i0) | ((unsigned int)f2bf(o0[dt][1] * i0) << 16);
      pk.y = (unsigned int)f2bf(o0[dt][2] * i0) | ((unsigned int)f2bf(o0[dt][3] * i0) << 16);
      *(uint2*)(or0 + dt * 16 + g4) = pk;
    }
  } else {
    const int tokp0 = qrow0 - HTOK;
    float* ob0;
    if (chunk < 2)
      ob0 = Opart + ((size_t)(chunk * NHT + tokp0) * HEADS + head) * HD;
    else
      ob0 = Opart2 + ((size_t)(tokp0 - 768) * HEADS + head) * HD;
#pragma unroll
    for (int dt = 0; dt < 8; ++dt)
      *(f32x4*)(ob0 + dt * 16 + g4) = o0[dt];
    if (lane < 16) {
      float* mlp0 = mlbuf + 2 * ((size_t)(chunk * NHT + tokp0) * HEADS + head);
      mlp0[0] = m0; mlp0[1] = l0;
    }
  }
}

// ---------------- merge the 2-or-3 K-chunks for heavy rows ----------------
__global__ __launch_bounds__(384)
void merge_k(const float* __restrict__ Opart, const float* __restrict__ Opart2,
             const float* __restrict__ mlbuf, unsigned short* __restrict__ ab)
{
  const int tokp = blockIdx.x;
  const int tid = threadIdx.x;
  const int e = tid * 4;
  const int head = e >> 7;
  const size_t r0 = (size_t)tokp * DIMC + e;
  float4 o0 = *(const float4*)(Opart + r0);
  float4 o1 = *(const float4*)(Opart + (size_t)NHT * DIMC + r0);
  const float* ml0 = mlbuf + 2 * ((size_t)tokp * HEADS + head);
  const float* ml1 = mlbuf + 2 * ((size_t)(NHT + tokp) * HEADS + head);
  const float m0 = ml0[0], l0 = ml0[1], m1 = ml1[0], l1 = ml1[1];

  const bool three = (tokp >= 768);             // qb>=15 rows have a 3rd chunk
  float m2 = -3.0e38f, l2 = 0.f;
  float4 o2 = make_float4(0.f, 0.f, 0.f, 0.f);
  if (three) {
    o2 = *(const float4*)(Opart2 + (size_t)(tokp - 768) * DIMC + e);
    const float* ml2 = mlbuf + 2 * ((size_t)(2 * NHT + tokp) * HEADS + head);
    m2 = ml2[0]; l2 = ml2[1];
  }

  const float mm = fmaxf(fmaxf(m0, m1), m2);
  const float a0 = exp2f(m0 - mm), a1 = exp2f(m1 - mm);
  const float a2 = three ? exp2f(m2 - mm) : 0.f;
  const float inv = 1.f / (l0 * a0 + l1 * a1 + l2 * a2);
  uint2 pk;
  pk.x = (unsigned int)f2bf((o0.x * a0 + o1.x * a1 + o2.x * a2) * inv) |
         ((unsigned int)f2bf((o0.y * a0 + o1.y * a1 + o2.y * a2) * inv) << 16);
  pk.y = (unsigned int)f2bf((o0.z * a0 + o1.z * a1 + o2.z * a2) * inv) |
         ((unsigned int)f2bf((o0.w * a0 + o1.w * a1 + o2.w * a2) * inv) << 16);
  *(uint2*)(ab + (size_t)(HTOK + tokp) * DIMC + e) = pk;
}

// ---------------- launch ----------------
extern "C" void kernel_launch(void* const* d_in, const int* in_sizes, int n_in,
                              void* d_out, int out_size, void* d_ws, size_t ws_size,
                              hipStream_t stream)
{
  (void)in_sizes; (void)n_in; (void)out_size; (void)ws_size;
  const float* x     = (const float*)d_in[0];
  const float* freqs = (const float*)d_in[3];
  const float* wq    = (const float*)d_in[4];
  const float* bq    = (const float*)d_in[5];
  const float* wk    = (const float*)d_in[6];
  const float* bk    = (const float*)d_in[7];
  const float* wv    = (const float*)d_in[8];
  const float* bv    = (const float*)d_in[9];
  const float* wo    = (const float*)d_in[10];
  const float* bo    = (const float*)d_in[11];
  const float* nqw   = (const float*)d_in[12];
  const float* nkw   = (const float*)d_in[13];

  char* ws = (char*)d_ws;
  size_t off = 0;
  auto take = [&](size_t bytes) -> void* {
    void* p = ws + off; off += (bytes + 255) & ~(size_t)255; return p;
  };
  unsigned short* wob = (unsigned short*)take((size_t)DIMC * DIMC * 2);
  unsigned short* qb  = (unsigned short*)take((size_t)LTOK * DIMC * 2);
  unsigned short* kb  = (unsigned short*)take((size_t)LTOK * DIMC * 2);
  unsigned short* vb  = (unsigned short*)take((size_t)LTOK * DIMC * 2);  // slot-2 partials
  unsigned short* ab  = (unsigned short*)take((size_t)LTOK * DIMC * 2);
  unsigned short* vtb = (unsigned short*)take((size_t)LTOK * DIMC * 2);
  unsigned short* xb  = (unsigned short*)take((size_t)LTOK * DIMC * 2);
  unsigned short* wqb = (unsigned short*)take((size_t)DIMC * DIMC * 2);
  unsigned short* wkb = (unsigned short*)take((size_t)DIMC * DIMC * 2);
  unsigned short* wvb = (unsigned short*)take((size_t)DIMC * DIMC * 2);
  float* mlb = (float*)take((size_t)3 * NHT * HEADS * 2 * sizeof(float));
  float* Opart  = (float*)xb;   // slots 0,1: overlays xb+wqb+wkb+wvb (dead after QKV GEMM)
  float* Opart2 = (float*)vb;   // slot 2: 1152 rows (qb>=15), 7.1 MB <= 9.4 MB

  cvt_all_k<<<dim3(13824), dim3(256), 0, stream>>>(x, wq, wk, wv, wo,
                                                   xb, wqb, wkb, wvb, wob);

  gemm_qkv<<<dim3(864), dim3(256), 0, stream>>>(
      xb, wqb, wkb, wvb, bq, bk, bv, qb, kb, vtb);

  post_qkv_k<<<dim3(2 * LTOK), dim3(192), 0, stream>>>(qb, kb, nqw, nkw, freqs);

  attn_flash<<<dim3(576), dim3(512), 0, stream>>>(qb, kb, vtb, ab, Opart, Opart2, mlb);
  merge_k<<<dim3(NHT), dim3(384), 0, stream>>>(Opart, Opart2, mlb, ab);

  gemm_wo<<<dim3(576), dim3(256), 0, stream>>>(
      ab, wob, bo, (float*)d_out);
}

// Round 11
// 270.920 us; speedup vs baseline: 1.3206x; 1.0422x over previous
//
#include <hip/hip_runtime.h>
#include <stdint.h>

#define DIMC 1536
#define LTOK 3072
#define HEADS 12
#define HD 128
#define FS 384            // H*W = 16*24
#define MAXATTN 1920
#define HTOK 1152         // first token with qf>=3 (chunked rows)
#define NHT 1920          // number of heavy tokens

typedef __attribute__((ext_vector_type(4))) float f32x4;
typedef __attribute__((ext_vector_type(8))) short bf16x8;
typedef __attribute__((ext_vector_type(4))) unsigned int u32x4;

__device__ __forceinline__ unsigned short f2bf(float f) {
  union { float f; unsigned int u; } c; c.f = f;
  unsigned int u = c.u + 0x7fffu + ((c.u >> 16) & 1u);   // RNE
  return (unsigned short)(u >> 16);
}
__device__ __forceinline__ float bf2f(unsigned short s) {
  union { unsigned int u; float f; } c; c.u = (unsigned int)s << 16; return c.f;
}
// packed 2xf32 -> 2xbf16 (RNE), one instruction
__device__ __forceinline__ unsigned int cvtpk(float a, float b) {
  unsigned int r;
  asm("v_cvt_pk_bf16_f32 %0, %1, %2" : "=v"(r) : "v"(a), "v"(b));
  return r;
}

// async global->LDS DMA, 16B per lane; LDS dest must be wave-uniform base +
// lane*16 (all our staging offsets are tid*16B -> satisfied).
__device__ __forceinline__ void dma16(const void* g, void* l) {
  __builtin_amdgcn_global_load_lds(
      (const __attribute__((address_space(1))) unsigned int*)g,
      (__attribute__((address_space(3))) unsigned int*)l, 16, 0, 0);
}

// key permutation inside each 64-key tile (4-token groups stay contiguous):
// group G bits (g3 g2 g1 g0) -> G' = g3*8 + g1*4 + g0*2 + g2, chosen so the
// attention PV B-operand fragment IS the softmax output registers.
__device__ __forceinline__ int vperm4(int G) {
  return (((G >> 3) & 1) << 3) | (((G >> 1) & 1) << 2) | ((G & 1) << 1) | ((G >> 2) & 1);
}

// ---------------- fused fp32 -> bf16 conversion for all 5 tensors ----------------
__global__ __launch_bounds__(256)
void cvt_all_k(const float* __restrict__ x, const float* __restrict__ wq,
               const float* __restrict__ wk, const float* __restrict__ wv,
               const float* __restrict__ wo,
               unsigned short* __restrict__ xb, unsigned short* __restrict__ wqb,
               unsigned short* __restrict__ wkb, unsigned short* __restrict__ wvb,
               unsigned short* __restrict__ wob)
{
  const int i = blockIdx.x * 256 + threadIdx.x;      // uint4 index
  const int n0 = LTOK * DIMC / 4;
  const int nw = DIMC * DIMC / 4;
  const float* src; unsigned short* dst; int off;
  if (i < n0) { src = x; dst = xb; off = i; }
  else {
    int j = i - n0; int w = j / nw; off = j - w * nw;
    src = (w == 0) ? wq : (w == 1) ? wk : (w == 2) ? wv : wo;
    dst = (w == 0) ? wqb : (w == 1) ? wkb : (w == 2) ? wvb : wob;
  }
  float4 f = ((const float4*)src)[off];
  uint2 o;
  o.x = (unsigned int)f2bf(f.x) | ((unsigned int)f2bf(f.y) << 16);
  o.y = (unsigned int)f2bf(f.z) | ((unsigned int)f2bf(f.w) << 16);
  ((uint2*)dst)[off] = o;
}

// ---------------- QKV GEMM: 128x128 tile, BK=64, 256 thr, single-buffer -------
// Single-buffer + XCD-chunked swizzle (T1): flat grid 864 = 8*108,
// f'=(f&7)*108+(f>>3) -> each XCD owns 9 contiguous A-panels.
__global__ __launch_bounds__(256)
void gemm_qkv(const unsigned short* __restrict__ A,
              const unsigned short* __restrict__ B0,
              const unsigned short* __restrict__ B1,
              const unsigned short* __restrict__ B2,
              const float* __restrict__ bias0,
              const float* __restrict__ bias1,
              const float* __restrict__ bias2,
              unsigned short* __restrict__ o0, unsigned short* __restrict__ o1,
              unsigned short* __restrict__ vt)
{
  const int f = blockIdx.x;
  const int fp = (f & 7) * 108 + (f >> 3);      // bijective: 864 = 8*108
  const int z = fp / 288;
  const int rr = fp - z * 288;
  const int by = rr / 12;
  const int bx = rr - by * 12;

  const unsigned short* Bw = (z == 0) ? B0 : (z == 1) ? B1 : B2;
  const float* bias = (z == 0) ? bias0 : (z == 1) ? bias1 : bias2;

  __shared__ __align__(16) unsigned short lA[128 * 64];
  __shared__ __align__(16) unsigned short lB[128 * 64];

  const int tid = threadIdx.x;
  const int wave = tid >> 6;
  const int lane = tid & 63;
  const int m0 = by * 128;
  const int n0 = bx * 128;
  const int wm = (wave >> 1) * 64;
  const int wn = (wave & 1) * 64;

  f32x4 acc[4][4] = {};

  const int srow = tid >> 3;                    // 0..31
  const int scol = ((tid & 7) ^ (srow & 7)) * 8;
  const unsigned short* ga = A  + (size_t)(m0 + srow) * DIMC + scol;
  const unsigned short* gb = Bw + (size_t)(n0 + srow) * DIMC + scol;
  unsigned short* la = lA + tid * 8;
  unsigned short* lb = lB + tid * 8;

  const int fr = lane & 15;
  const int g = lane >> 4;
  const int fx = fr & 7;                        // read-side XOR term

  for (int k0 = 0; k0 < DIMC; k0 += 64) {
    dma16(ga + k0,                     la);
    dma16(ga + k0 + (size_t)32 * DIMC, la + 2048);
    dma16(ga + k0 + (size_t)64 * DIMC, la + 4096);
    dma16(ga + k0 + (size_t)96 * DIMC, la + 6144);
    dma16(gb + k0,                     lb);
    dma16(gb + k0 + (size_t)32 * DIMC, lb + 2048);
    dma16(gb + k0 + (size_t)64 * DIMC, lb + 4096);
    dma16(gb + k0 + (size_t)96 * DIMC, lb + 6144);
    __syncthreads();

#pragma unroll
    for (int kk = 0; kk < 2; ++kk) {
      const int cx = ((kk * 4 + g) ^ fx) * 8;   // swizzled chunk offset
      bf16x8 af[4], bf[4];
#pragma unroll
      for (int i = 0; i < 4; ++i)
        af[i] = *(const bf16x8*)&lA[(wm + i * 16 + fr) * 64 + cx];
#pragma unroll
      for (int j = 0; j < 4; ++j)
        bf[j] = *(const bf16x8*)&lB[(wn + j * 16 + fr) * 64 + cx];
#pragma unroll
      for (int i = 0; i < 4; ++i)
#pragma unroll
        for (int j = 0; j < 4; ++j)
          acc[i][j] = __builtin_amdgcn_mfma_f32_16x16x32_bf16(af[i], bf[j], acc[i][j], 0, 0, 0);
    }
    __syncthreads();
  }

  const int col = lane & 15;
  const int rb = (lane >> 4) * 4;
  if (z < 2) {
    unsigned short* outp = z ? o1 : o0;
#pragma unroll
    for (int j = 0; j < 4; ++j) {
      const int gn = n0 + wn + j * 16 + col;
      const float bv = bias[gn];
#pragma unroll
      for (int i = 0; i < 4; ++i)
#pragma unroll
        for (int r = 0; r < 4; ++r) {
          const int gm = m0 + wm + i * 16 + rb + r;
          outp[(size_t)gm * DIMC + gn] = f2bf(acc[i][j][r] + bv);
        }
    }
  } else {
    // vt[d][tok'] = v[tok][d] + bias, tok' = 64-tile base + vperm4(group)*4 + r
#pragma unroll
    for (int j = 0; j < 4; ++j) {
      const int gn = n0 + wn + j * 16 + col;      // d
      const float bv = bias[gn];
#pragma unroll
      for (int i = 0; i < 4; ++i) {
        const int base = wm + i * 16 + rb;        // within-128, multiple of 4
        const int tile = base & ~63;
        const int toka = m0 + tile + vperm4((base & 63) >> 2) * 4;
        uint2 pk;
        pk.x = (unsigned int)f2bf(acc[i][j][0] + bv) |
               ((unsigned int)f2bf(acc[i][j][1] + bv) << 16);
        pk.y = (unsigned int)f2bf(acc[i][j][2] + bv) |
               ((unsigned int)f2bf(acc[i][j][3] + bv) << 16);
        *(uint2*)(vt + (size_t)gn * LTOK + toka) = pk;
      }
    }
  }
}

// ---------------- wo GEMM: 64x128 tile, BK=64, single-buffer + T1 swizzle -----
// Flat grid 576 = 8*72; A-sharers (12 n-blocks per m-row) co-located per XCD.
// (128^2 @ 288 blocks measured worse: grid quantization at 1.125 blocks/CU.)
__global__ __launch_bounds__(256)
void gemm_wo(const unsigned short* __restrict__ A,
             const unsigned short* __restrict__ Bw,
             const float* __restrict__ bias,
             float* __restrict__ outp)
{
  const int f = blockIdx.x;
  const int fp = (f & 7) * 72 + (f >> 3);       // bijective: 576 = 8*72
  const int by = fp / 12;
  const int bx = fp - by * 12;

  __shared__ __align__(16) unsigned short lA[64 * 64];
  __shared__ __align__(16) unsigned short lB[128 * 64];

  const int tid = threadIdx.x;
  const int wave = tid >> 6;
  const int lane = tid & 63;
  const int m0 = by * 64;
  const int n0 = bx * 128;
  const int wm = (wave >> 1) * 32;
  const int wn = (wave & 1) * 64;

  f32x4 acc[2][4] = {};

  const int srow = tid >> 3;                    // 0..31
  const int scol = ((tid & 7) ^ (srow & 7)) * 8;
  const unsigned short* ga = A  + (size_t)(m0 + srow) * DIMC + scol;
  const unsigned short* gb = Bw + (size_t)(n0 + srow) * DIMC + scol;
  unsigned short* la = lA + tid * 8;
  unsigned short* lb = lB + tid * 8;

  const int fr = lane & 15;
  const int g = lane >> 4;
  const int fx = fr & 7;

  for (int k0 = 0; k0 < DIMC; k0 += 64) {
    dma16(ga + k0,                     la);
    dma16(ga + k0 + (size_t)32 * DIMC, la + 2048);
    dma16(gb + k0,                     lb);
    dma16(gb + k0 + (size_t)32 * DIMC, lb + 2048);
    dma16(gb + k0 + (size_t)64 * DIMC, lb + 4096);
    dma16(gb + k0 + (size_t)96 * DIMC, lb + 6144);
    __syncthreads();

#pragma unroll
    for (int kk = 0; kk < 2; ++kk) {
      const int cx = ((kk * 4 + g) ^ fx) * 8;
      bf16x8 af[2], bf[4];
#pragma unroll
      for (int i = 0; i < 2; ++i)
        af[i] = *(const bf16x8*)&lA[(wm + i * 16 + fr) * 64 + cx];
#pragma unroll
      for (int j = 0; j < 4; ++j)
        bf[j] = *(const bf16x8*)&lB[(wn + j * 16 + fr) * 64 + cx];
#pragma unroll
      for (int i = 0; i < 2; ++i)
#pragma unroll
        for (int j = 0; j < 4; ++j)
          acc[i][j] = __builtin_amdgcn_mfma_f32_16x16x32_bf16(af[i], bf[j], acc[i][j], 0, 0, 0);
    }
    __syncthreads();
  }

  const int col = lane & 15;
  const int rb = (lane >> 4) * 4;
#pragma unroll
  for (int j = 0; j < 4; ++j) {
    const int gn = n0 + wn + j * 16 + col;
    const float bv = bias[gn];
#pragma unroll
    for (int i = 0; i < 2; ++i)
#pragma unroll
      for (int r = 0; r < 4; ++r) {
        const int gm = m0 + wm + i * 16 + rb + r;
        outp[(size_t)gm * DIMC + gn] = acc[i][j][r] + bv;
      }
  }
}

// ---------------- rmsnorm + 3D RoPE on q/k, vectorized (G13) ------------------
// 192 threads x 8 bf16 (16B aligned loads/stores), float4 nw, float2 freqs.
__global__ __launch_bounds__(192)
void post_qkv_k(unsigned short* __restrict__ q, unsigned short* __restrict__ k,
                const float* __restrict__ nqw, const float* __restrict__ nkw,
                const float* __restrict__ freqs)
{
  const int bx = blockIdx.x;
  const int tid = threadIdx.x;
  const int which = bx >= LTOK;
  const int tok = bx - which * LTOK;
  unsigned short* row = (which ? k : q) + (size_t)tok * DIMC;
  const float* nw = which ? nkw : nqw;
  const float sc = which ? 1.f : (0.08838834764831845f * 1.4426950408889634f);
  const int base = tid * 8;

  const bf16x8 rv = *(const bf16x8*)(row + base);
  float vv[8];
  float ss = 0.f;
#pragma unroll
  for (int j = 0; j < 8; ++j) {
    vv[j] = bf2f((unsigned short)rv[j]);
    ss += vv[j] * vv[j];
  }
#pragma unroll
  for (int off = 1; off < 64; off <<= 1) ss += __shfl_xor(ss, off);
  __shared__ float wsum[3];
  if ((tid & 63) == 0) wsum[tid >> 6] = ss;
  __syncthreads();
  const float total = wsum[0] + wsum[1] + wsum[2];
  const float rms = rsqrtf(total * (1.f / DIMC) + 1e-6f);

  const int f = tok / FS;
  const int rem = tok - f * FS;
  const int h = rem / 24;
  const int w = rem - h * 24;

  float nwv[8];
  *(float4*)&nwv[0] = *(const float4*)(nw + base);
  *(float4*)&nwv[4] = *(const float4*)(nw + base + 4);

  u32x4 outp;
#pragma unroll
  for (int pp = 0; pp < 4; ++pp) {
    const int P = (base >> 1) + pp;
    const int p = P & 63;
    const int t = (p < 22) ? f : ((p < 43) ? h : w);
    const float2 fc = *(const float2*)(freqs + t * 128 + p * 2);
    const float e = vv[2 * pp]     * rms * nwv[2 * pp];
    const float o = vv[2 * pp + 1] * rms * nwv[2 * pp + 1];
    outp[pp] = (unsigned int)f2bf((e * fc.x - o * fc.y) * sc) |
               ((unsigned int)f2bf((e * fc.y + o * fc.x) * sc) << 16);
  }
  *(u32x4*)(row + base) = outp;
}

// ---------------- MFMA flash attention v11: single-buffered V -----------------
// v6 compute unchanged; LDS 64->48 KB (K dbuf 32 KB + V single 16 KB) ->
// 3 blocks/CU (was 2), 6 waves/SIMD, and the whole 576-block grid co-resident
// (was capacity 512 -> 64-block tail). Sync: raw s_barrier + counted vmcnt.
//   iter top: vmcnt(0) [K(t) landed] + barrier A [V buffer WAR-free]
//   stage V(t) then K(t+1)  (issue order matters: vmcnt is in-order)
//   QK + softmax
//   vmcnt(2) [V's 2 loads done; K(t+1)'s 2 still in flight] + barrier B
//   PV from single V buffer
// V overlap = QK+softmax (~2000 cyc) >> HBM latency; K overlap unchanged (full
// iteration). Tail iter (no K prefetch) uses vmcnt(0) before barrier B.
#define KBUF (64 * 128)
#define VBUF (128 * 64)
__global__ __launch_bounds__(512, 4)
void attn_flash(const unsigned short* __restrict__ q,
                const unsigned short* __restrict__ k,
                const unsigned short* __restrict__ vt,
                unsigned short* __restrict__ ab,
                float* __restrict__ Opart,
                float* __restrict__ Opart2,
                float* __restrict__ mlbuf)
{
  const int bid = blockIdx.x;
  int qb, head, chunk, nch;
  if (bid < 36)       { qb = 6 + bid / 12; head = bid % 12; chunk = 0; nch = 1; }         // 18-tile
  else if (bid < 108) { int b = bid - 36;  qb = 12 + b / 24; int r = b % 24; head = r >> 1; chunk = r & 1; nch = 2; }  // 15-tile
  else if (bid < 432) { int b = bid - 108; qb = 15 + b / 36; int r = b % 36; head = r / 3; chunk = r % 3; nch = 3; }   // 12-tile
  else if (bid < 504) { int b = bid - 432; qb = 9 + b / 24;  int r = b % 24; head = r >> 1; chunk = r & 1; nch = 2; }  // 12-tile
  else if (bid < 540) { int b = bid - 504; qb = 3 + b / 12; head = b % 12; chunk = 0; nch = 1; }  // 12-tile
  else                { int b = bid - 540; qb = b / 12;     head = b % 12; chunk = 0; nch = 1; }  // 6-tile

  const int q0 = qb * 128;
  const int qf = qb / 3;
  const int kend = (qf + 1) * FS;
  const int s2 = kend - MAXATTN;
  const bool two = (s2 > FS);
  const int nt1 = (two ? FS : kend) >> 6;
  const int nt  = nt1 + (two ? (MAXATTN >> 6) : 0);
  const int half = nt / nch;
  const int tstart = chunk * half, tend = tstart + half;

  const int tid = threadIdx.x;
  const int wave = tid >> 6, lane = tid & 63;
  const int col = lane & 15;
  const int g = lane >> 4;
  const int g4 = g * 4;

  __shared__ __align__(16) unsigned short Kl[2 * KBUF];   // 32 KB (dbuf)
  __shared__ __align__(16) unsigned short Vtl[VBUF];      // 16 KB (single)

  bf16x8 qfA[4];
  {
    const unsigned short* qr0 = q + (size_t)(q0 + wave * 16 + col) * DIMC + head * HD;
#pragma unroll
    for (int kk = 0; kk < 4; ++kk)
      qfA[kk] = *(const bf16x8*)(qr0 + kk * 32 + g * 8);
  }

  f32x4 o0[8] = {};
  float m0 = -3.0e38f, l0 = 0.f;

  const int krow = tid >> 4;
  const int kc8  = ((tid & 15) ^ (krow & 15)) * 8;
  const unsigned short* kg = k + (size_t)krow * DIMC + head * HD + kc8;
  const int vrow = tid >> 3;
  const int vc8  = ((tid & 7) ^ (vrow & 7)) * 8;
  const unsigned short* vg = vt + ((size_t)head * HD + vrow) * LTOK + vc8;
  unsigned short* kl = Kl + tid * 8;
  unsigned short* vl = Vtl + tid * 8;

  // prologue: stage K(tstart) only (V staged per-iteration)
  {
    const int kb = (tstart < nt1) ? tstart * 64 : s2 + (tstart - nt1) * 64;
    const unsigned short* kp = kg + (size_t)kb * DIMC;
    dma16(kp,                     kl);
    dma16(kp + (size_t)32 * DIMC, kl + 32 * 128);
  }

  for (int t = tstart; t < tend; ++t) {
    const int kcur = ((t - tstart) & 1) * KBUF;

    asm volatile("s_waitcnt vmcnt(0)" ::: "memory");   // K(t) landed
    __builtin_amdgcn_s_barrier();                       // [A] cross-wave; V WAR-free
    __builtin_amdgcn_sched_barrier(0);

    // stage V(t) FIRST (in-order completion -> vmcnt(2) below covers it)
    {
      const int kb = (t < nt1) ? t * 64 : s2 + (t - nt1) * 64;
      const unsigned short* vp = vg + kb;
      dma16(vp,                     vl);
      dma16(vp + (size_t)64 * LTOK, vl + 64 * 64);
    }
    const bool pf = (t + 1 < tend);
    if (pf) {
      const int kb = (t + 1 < nt1) ? (t + 1) * 64 : s2 + (t + 1 - nt1) * 64;
      const int knxt = KBUF - kcur;
      const unsigned short* kp = kg + (size_t)kb * DIMC;
      dma16(kp,                     kl + knxt);
      dma16(kp + (size_t)32 * DIMC, kl + knxt + 32 * 128);
    }

    f32x4 sA[4] = {};
    __builtin_amdgcn_s_setprio(1);
#pragma unroll
    for (int kt = 0; kt < 4; ++kt) {
      const unsigned short* kr = &Kl[kcur + (kt * 16 + col) * 128];
#pragma unroll
      for (int kk = 0; kk < 4; ++kk) {
        bf16x8 kfr = *(const bf16x8*)(kr + ((kk * 4 + g) ^ col) * 8);
        sA[kt] = __builtin_amdgcn_mfma_f32_16x16x32_bf16(kfr, qfA[kk], sA[kt], 0, 0, 0);
      }
    }
    __builtin_amdgcn_s_setprio(0);

    // row max (tree) over 16 local scores + cross-lane halves
    float mxa = fmaxf(fmaxf(sA[0][0], sA[0][1]), fmaxf(sA[0][2], sA[0][3]));
    float mxb = fmaxf(fmaxf(sA[1][0], sA[1][1]), fmaxf(sA[1][2], sA[1][3]));
    float mxc = fmaxf(fmaxf(sA[2][0], sA[2][1]), fmaxf(sA[2][2], sA[2][3]));
    float mxd = fmaxf(fmaxf(sA[3][0], sA[3][1]), fmaxf(sA[3][2], sA[3][3]));
    float mx = fmaxf(fmaxf(mxa, mxb), fmaxf(mxc, mxd));
    mx = fmaxf(mx, __shfl_xor(mx, 16));
    mx = fmaxf(mx, __shfl_xor(mx, 32));

    // defer-max: only rescale when the tile max exceeds running max by >8
    if (!__all(mx <= m0 + 8.f)) {
      const float mn = fmaxf(m0, mx);
      const float al = exp2f(m0 - mn);
      m0 = mn;
      l0 *= al;
#pragma unroll
      for (int dt = 0; dt < 8; ++dt) o0[dt] *= al;
    }

    float p[16];
#pragma unroll
    for (int kt = 0; kt < 4; ++kt)
#pragma unroll
      for (int r = 0; r < 4; ++r)
        p[kt * 4 + r] = exp2f(sA[kt][r] - m0);

    float rs = ((p[0] + p[1]) + (p[2] + p[3])) + ((p[4] + p[5]) + (p[6] + p[7]))
             + ((p[8] + p[9]) + (p[10] + p[11])) + ((p[12] + p[13]) + (p[14] + p[15]));
    rs += __shfl_xor(rs, 16);
    rs += __shfl_xor(rs, 32);
    l0 += rs;

    u32x4 tA0, tA1;
    tA0[0] = cvtpk(p[0], p[1]);   tA0[1] = cvtpk(p[2], p[3]);
    tA0[2] = cvtpk(p[4], p[5]);   tA0[3] = cvtpk(p[6], p[7]);
    tA1[0] = cvtpk(p[8], p[9]);   tA1[1] = cvtpk(p[10], p[11]);
    tA1[2] = cvtpk(p[12], p[13]); tA1[3] = cvtpk(p[14], p[15]);
    const bf16x8 pfA0 = __builtin_bit_cast(bf16x8, tA0);
    const bf16x8 pfA1 = __builtin_bit_cast(bf16x8, tA1);

    // V(t) visible: own V loads done (vmcnt counts in order; K prefetch may fly)
    if (pf) asm volatile("s_waitcnt vmcnt(2)" ::: "memory");
    else    asm volatile("s_waitcnt vmcnt(0)" ::: "memory");
    __builtin_amdgcn_s_barrier();                       // [B] cross-wave V ready
    __builtin_amdgcn_sched_barrier(0);

    const int vx0 = (g ^ (col & 7)) * 8;
    const int vx1 = ((4 + g) ^ (col & 7)) * 8;
    __builtin_amdgcn_s_setprio(1);
#pragma unroll
    for (int dt = 0; dt < 8; ++dt) {
      const unsigned short* vr = &Vtl[(dt * 16 + col) * 64];
      bf16x8 vf0 = *(const bf16x8*)(vr + vx0);
      o0[dt] = __builtin_amdgcn_mfma_f32_16x16x32_bf16(vf0, pfA0, o0[dt], 0, 0, 0);
      bf16x8 vf1 = *(const bf16x8*)(vr + vx1);
      o0[dt] = __builtin_amdgcn_mfma_f32_16x16x32_bf16(vf1, pfA1, o0[dt], 0, 0, 0);
    }
    __builtin_amdgcn_s_setprio(0);
  }

  const int qrow0 = q0 + wave * 16 + col;
  if (nch == 1) {
    const float i0 = 1.f / l0;
    unsigned short* or0 = ab + (size_t)qrow0 * DIMC + head * HD;
#pragma unroll
    for (int dt = 0; dt < 8; ++dt) {
      uint2 pk;
      pk.x = (unsigned int)f2bf(o0[dt][0] * i0) | ((unsigned int)f2bf(o0[dt][1] * i0) << 16);
      pk.y = (unsigned int)f2bf(o0[dt][2] * i0) | ((unsigned int)f2bf(o0[dt][3] * i0) << 16);
      *(uint2*)(or0 + dt * 16 + g4) = pk;
    }
  } else {
    const int tokp0 = qrow0 - HTOK;
    float* ob0;
    if (chunk < 2)
      ob0 = Opart + ((size_t)(chunk * NHT + tokp0) * HEADS + head) * HD;
    else
      ob0 = Opart2 + ((size_t)(tokp0 - 768) * HEADS + head) * HD;
#pragma unroll
    for (int dt = 0; dt < 8; ++dt)
      *(f32x4*)(ob0 + dt * 16 + g4) = o0[dt];
    if (lane < 16) {
      float* mlp0 = mlbuf + 2 * ((size_t)(chunk * NHT + tokp0) * HEADS + head);
      mlp0[0] = m0; mlp0[1] = l0;
    }
  }
}

// ---------------- merge the 2-or-3 K-chunks for heavy rows ----------------
__global__ __launch_bounds__(384)
void merge_k(const float* __restrict__ Opart, const float* __restrict__ Opart2,
             const float* __restrict__ mlbuf, unsigned short* __restrict__ ab)
{
  const int tokp = blockIdx.x;
  const int tid = threadIdx.x;
  const int e = tid * 4;
  const int head = e >> 7;
  const size_t r0 = (size_t)tokp * DIMC + e;
  float4 o0 = *(const float4*)(Opart + r0);
  float4 o1 = *(const float4*)(Opart + (size_t)NHT * DIMC + r0);
  const float* ml0 = mlbuf + 2 * ((size_t)tokp * HEADS + head);
  const float* ml1 = mlbuf + 2 * ((size_t)(NHT + tokp) * HEADS + head);
  const float m0 = ml0[0], l0 = ml0[1], m1 = ml1[0], l1 = ml1[1];

  const bool three = (tokp >= 768);             // qb>=15 rows have a 3rd chunk
  float m2 = -3.0e38f, l2 = 0.f;
  float4 o2 = make_float4(0.f, 0.f, 0.f, 0.f);
  if (three) {
    o2 = *(const float4*)(Opart2 + (size_t)(tokp - 768) * DIMC + e);
    const float* ml2 = mlbuf + 2 * ((size_t)(2 * NHT + tokp) * HEADS + head);
    m2 = ml2[0]; l2 = ml2[1];
  }

  const float mm = fmaxf(fmaxf(m0, m1), m2);
  const float a0 = exp2f(m0 - mm), a1 = exp2f(m1 - mm);
  const float a2 = three ? exp2f(m2 - mm) : 0.f;
  const float inv = 1.f / (l0 * a0 + l1 * a1 + l2 * a2);
  uint2 pk;
  pk.x = (unsigned int)f2bf((o0.x * a0 + o1.x * a1 + o2.x * a2) * inv) |
         ((unsigned int)f2bf((o0.y * a0 + o1.y * a1 + o2.y * a2) * inv) << 16);
  pk.y = (unsigned int)f2bf((o0.z * a0 + o1.z * a1 + o2.z * a2) * inv) |
         ((unsigned int)f2bf((o0.w * a0 + o1.w * a1 + o2.w * a2) * inv) << 16);
  *(uint2*)(ab + (size_t)(HTOK + tokp) * DIMC + e) = pk;
}

// ---------------- launch ----------------
extern "C" void kernel_launch(void* const* d_in, const int* in_sizes, int n_in,
                              void* d_out, int out_size, void* d_ws, size_t ws_size,
                              hipStream_t stream)
{
  (void)in_sizes; (void)n_in; (void)out_size; (void)ws_size;
  const float* x     = (const float*)d_in[0];
  const float* freqs = (const float*)d_in[3];
  const float* wq    = (const float*)d_in[4];
  const float* bq    = (const float*)d_in[5];
  const float* wk    = (const float*)d_in[6];
  const float* bk    = (const float*)d_in[7];
  const float* wv    = (const float*)d_in[8];
  const float* bv    = (const float*)d_in[9];
  const float* wo    = (const float*)d_in[10];
  const float* bo    = (const float*)d_in[11];
  const float* nqw   = (const float*)d_in[12];
  const float* nkw   = (const float*)d_in[13];

  char* ws = (char*)d_ws;
  size_t off = 0;
  auto take = [&](size_t bytes) -> void* {
    void* p = ws + off; off += (bytes + 255) & ~(size_t)255; return p;
  };
  unsigned short* wob = (unsigned short*)take((size_t)DIMC * DIMC * 2);
  unsigned short* qb  = (unsigned short*)take((size_t)LTOK * DIMC * 2);
  unsigned short* kb  = (unsigned short*)take((size_t)LTOK * DIMC * 2);
  unsigned short* vb  = (unsigned short*)take((size_t)LTOK * DIMC * 2);  // slot-2 partials
  unsigned short* ab  = (unsigned short*)take((size_t)LTOK * DIMC * 2);
  unsigned short* vtb = (unsigned short*)take((size_t)LTOK * DIMC * 2);
  unsigned short* xb  = (unsigned short*)take((size_t)LTOK * DIMC * 2);
  unsigned short* wqb = (unsigned short*)take((size_t)DIMC * DIMC * 2);
  unsigned short* wkb = (unsigned short*)take((size_t)DIMC * DIMC * 2);
  unsigned short* wvb = (unsigned short*)take((size_t)DIMC * DIMC * 2);
  float* mlb = (float*)take((size_t)3 * NHT * HEADS * 2 * sizeof(float));
  float* Opart  = (float*)xb;   // slots 0,1: overlays xb+wqb+wkb+wvb (dead after QKV GEMM)
  float* Opart2 = (float*)vb;   // slot 2: 1152 rows (qb>=15), 7.1 MB <= 9.4 MB

  cvt_all_k<<<dim3(13824), dim3(256), 0, stream>>>(x, wq, wk, wv, wo,
                                                   xb, wqb, wkb, wvb, wob);

  gemm_qkv<<<dim3(864), dim3(256), 0, stream>>>(
      xb, wqb, wkb, wvb, bq, bk, bv, qb, kb, vtb);

  post_qkv_k<<<dim3(2 * LTOK), dim3(192), 0, stream>>>(qb, kb, nqw, nkw, freqs);

  attn_flash<<<dim3(576), dim3(512), 0, stream>>>(qb, kb, vtb, ab, Opart, Opart2, mlb);
  merge_k<<<dim3(NHT), dim3(384), 0, stream>>>(Opart, Opart2, mlb, ab);

  gemm_wo<<<dim3(576), dim3(256), 0, stream>>>(
      ab, wob, bo, (float*)d_out);
}